// Round 12
// baseline (1095.470 us; speedup 1.0000x reference)
//
#include <hip/hip_runtime.h>
#include <hip/hip_bf16.h>
#include <math.h>

#define BB 8
#define CC 16
#define HH 112
#define WW 112
#define KK 9
#define FS 9
#define WIN 7
#define DIM 160
#define HEADS 5
#define HDIM 32
#define MLPD 640
#define NWIN 256          // (112/7)^2
#define NPOS (BB*HH*WW)   // 100352

typedef __attribute__((ext_vector_type(8))) short short8;
typedef __attribute__((ext_vector_type(4))) float floatx4;

__device__ __forceinline__ unsigned short f2bf(float f) {
  union { float f; unsigned u; } v; v.f = f;
  unsigned r = v.u + 0x7fffu + ((v.u >> 16) & 1u);
  return (unsigned short)(r >> 16);
}
__device__ __forceinline__ float bf2f(unsigned short u) {
  union { unsigned u; float f; } v; v.u = ((unsigned)u) << 16;
  return v.f;
}
// gelu tanh-approx, exp-based (same formula as jax.nn.gelu, no libm tanh)
__device__ __forceinline__ float gelu_f(float a) {
  float z = 0.7978845608028654f * (a + 0.044715f * a * a * a);
  return a * __builtin_amdgcn_rcpf(1.f + __expf(-2.f * z));
}
// x3 uses internal channel order ch' = c*10 + k (k=0..8 subbands, 9 = relu skip).
__device__ __forceinline__ int orig_ch(int ch) {
  int c = ch / 10, k = ch - c * 10;
  return (k < 9) ? k * 16 + c : 144 + c;
}

// ---------------------------------------------------------------------------
// Kernel A: relu + analysis filter bank -> x3 (permuted channels).
// 16x16 tile, grid 392, ONE THREAD owns each position's full 640B channel row
// (the only write scheme measured clean — wave/block splits caused ~12x RMW).
// 4-channel grouping: 13 LDS reads feed 36 FMAs (ana was LDS-issue-bound).
// ---------------------------------------------------------------------------
__global__ __launch_bounds__(256) void ana_kernel(const float* __restrict__ x,
                                                  const float* __restrict__ fana,
                                                  float* __restrict__ x3) {
  __shared__ float tileS[16 * 576];  // 16 ch x 24x24
  __shared__ float fs[729];
  int tid = threadIdx.x;
  int blk = blockIdx.x;
  int b = blk / 49;
  int tile = blk - b * 49;
  int y0 = (tile / 7) * 16, x0 = (tile % 7) * 16;

  for (int i = tid; i < 729; i += 256) fs[i] = fana[i];
  for (int idx = tid; idx < 9216; idx += 256) {
    int c = idx / 576, r = idx - c * 576;
    int ly = r / 24, lx = r - ly * 24;
    int gy = y0 + ly - 4, gx = x0 + lx - 4;
    float v = 0.f;
    if (gy >= 0 && gy < HH && gx >= 0 && gx < WW)
      v = fmaxf(x[(((long)b * CC + c) * HH + gy) * WW + gx], 0.f);
    tileS[idx] = v;
  }
  __syncthreads();

  int ty = tid >> 4, tx = tid & 15;
  long obase = (((long)b * HH + (y0 + ty)) * WW + (x0 + tx)) * DIM;
  for (int cg = 0; cg < 4; cg++) {
    float acc[4][9];
#pragma unroll
    for (int cl = 0; cl < 4; cl++)
#pragma unroll
      for (int k = 0; k < 9; k++) acc[cl][k] = 0.f;
    const float* ts0 = &tileS[(cg * 4 + 0) * 576];
    const float* ts1 = &tileS[(cg * 4 + 1) * 576];
    const float* ts2 = &tileS[(cg * 4 + 2) * 576];
    const float* ts3 = &tileS[(cg * 4 + 3) * 576];
    for (int ky = 0; ky < 9; ky++) {
      for (int kx = 0; kx < 9; kx++) {
        int toff = (ty + ky) * 24 + (tx + kx);
        float f[9];
#pragma unroll
        for (int k = 0; k < 9; k++) f[k] = fs[k * 81 + ky * 9 + kx];
        float v0 = ts0[toff], v1 = ts1[toff], v2 = ts2[toff], v3 = ts3[toff];
#pragma unroll
        for (int k = 0; k < 9; k++) {
          acc[0][k] += v0 * f[k];
          acc[1][k] += v1 * f[k];
          acc[2][k] += v2 * f[k];
          acc[3][k] += v3 * f[k];
        }
      }
    }
    int center = (ty + 4) * 24 + (tx + 4);
    const float* tsp[4] = {ts0, ts1, ts2, ts3};
#pragma unroll
    for (int cl = 0; cl < 4; cl++) {
      int c = cg * 4 + cl;
      float skip = tsp[cl][center];
      float2* dst = (float2*)&x3[obase + c * 10];
      dst[0] = make_float2(acc[cl][0], acc[cl][1]);
      dst[1] = make_float2(acc[cl][2], acc[cl][3]);
      dst[2] = make_float2(acc[cl][4], acc[cl][5]);
      dst[3] = make_float2(acc[cl][6], acc[cl][7]);
      dst[4] = make_float2(acc[cl][8], skip);
    }
  }
}

// ---------------------------------------------------------------------------
// token_pos: window-ordered flat token p -> source position in [B,H,W]
// ---------------------------------------------------------------------------
__device__ __forceinline__ int token_pos(int p, int shift) {
  int w = p / 49;
  int t = p - w * 49;
  int b = w >> 8;
  int wid = w & 255;
  int wi = wid >> 4, wj = wid & 15;
  int iy = t / 7, ix = t - (t / 7) * 7;
  int hy = (wi * 7 + iy + shift) % HH;
  int wx = (wj * 7 + ix + shift) % WW;
  return (b * HH + hy) * WW + wx;
}

// ---------------------------------------------------------------------------
// Weight packing: fp32 [K x ncols] -> bf16 MFMA B-fragment-major layout.
// ---------------------------------------------------------------------------
__device__ __forceinline__ void pack_one(const float* __restrict__ src,
                                         unsigned short* __restrict__ dst,
                                         int nfcnt, int ncols, int nelems,
                                         int permK, int permN, int idx) {
  if (idx >= nelems) return;
  int j = idx & 7;
  int lane = (idx >> 3) & 63;
  int t = idx >> 9;
  int nf = t % nfcnt, ks = t / nfcnt;
  int k = ks * 32 + (lane >> 4) * 8 + j;
  int n = nf * 16 + (lane & 15);
  if (permK) k = orig_ch(k);
  if (permN) n = orig_ch(n);
  dst[idx] = f2bf(src[k * ncols + n]);
}

__global__ __launch_bounds__(256) void pack4_kernel(const float* __restrict__ qkvw,
                                                    const float* __restrict__ projw,
                                                    const float* __restrict__ w1,
                                                    const float* __restrict__ w2,
                                                    unsigned short* __restrict__ qkvf,
                                                    unsigned short* __restrict__ projf,
                                                    unsigned short* __restrict__ w1f,
                                                    unsigned short* __restrict__ w2f) {
  int blk = blockIdx.x, tid = threadIdx.x;
  if (blk < 300)      pack_one(qkvw,  qkvf,  30, 480, 76800,  1, 0, blk * 256 + tid);
  else if (blk < 400) pack_one(projw, projf, 10, 160, 25600,  0, 1, (blk - 300) * 256 + tid);
  else if (blk < 800) pack_one(w1,    w1f,   40, 640, 102400, 1, 0, (blk - 400) * 256 + tid);
  else                pack_one(w2,    w2f,   10, 160, 102400, 0, 1, (blk - 800) * 256 + tid);
}

__global__ __launch_bounds__(256) void pack1_kernel(const float* __restrict__ src,
                                                    unsigned short* __restrict__ dst,
                                                    int nfcnt, int ncols, int nelems,
                                                    int permK, int permN) {
  pack_one(src, dst, nfcnt, ncols, nelems, permK, permN, blockIdx.x * 256 + threadIdx.x);
}

// ---------------------------------------------------------------------------
// Kernel B1: LN1 + qkv GEMM via bf16 MFMA. 64 tokens/block (window-ordered).
// ---------------------------------------------------------------------------
__global__ __launch_bounds__(256) void qkv_mfma(const float* __restrict__ x3,
                                                const float* __restrict__ g,
                                                const float* __restrict__ bb,
                                                const unsigned short* __restrict__ qkvf,
                                                const float* __restrict__ qkvb,
                                                unsigned short* __restrict__ qkvbuf,
                                                int shift) {
  __shared__ unsigned short lnv[64 * 168];  // bf16, row stride 168

  int tid = threadIdx.x;
  int p0 = blockIdx.x * 64;

  {
    int t = tid >> 2, sub = tid & 3;
    int pos = token_pos(p0 + t, shift);
    const float* row = x3 + (long)pos * 160 + sub * 40;
    float xv[40];
    float s1 = 0.f, s2 = 0.f;
#pragma unroll
    for (int m = 0; m < 40; m++) { float v = row[m]; xv[m] = v; s1 += v; s2 += v * v; }
    s1 += __shfl_xor(s1, 1); s2 += __shfl_xor(s2, 1);
    s1 += __shfl_xor(s1, 2); s2 += __shfl_xor(s2, 2);
    float mu = s1 * (1.f / 160.f);
    float rs = rsqrtf(s2 * (1.f / 160.f) - mu * mu + 1e-5f);
#pragma unroll
    for (int m = 0; m < 40; m++) {
      int c = sub * 40 + m;
      int oc = orig_ch(c);
      lnv[t * 168 + c] = f2bf((xv[m] - mu) * rs * g[oc] + bb[oc]);
    }
  }
  __syncthreads();

  int w = tid >> 6, lane = tid & 63, quad = lane >> 4, l16 = lane & 15;

#pragma unroll
  for (int half = 0; half < 2; half++) {
    floatx4 acc[15];
#pragma unroll
    for (int n = 0; n < 15; n++) acc[n] = (floatx4){0.f, 0.f, 0.f, 0.f};
    for (int ks = 0; ks < 5; ks++) {
      short8 a = *(const short8*)&lnv[(w * 16 + l16) * 168 + ks * 32 + quad * 8];
      const short8* bp = (const short8*)qkvf + (ks * 30 + half * 15) * 64 + lane;
#pragma unroll
      for (int n = 0; n < 15; n++)
        acc[n] = __builtin_amdgcn_mfma_f32_16x16x32_bf16(a, bp[n * 64], acc[n], 0, 0, 0);
    }
#pragma unroll
    for (int n = 0; n < 15; n++) {
      int col = (half * 15 + n) * 16 + l16;
      float bv = qkvb[col];
#pragma unroll
      for (int r = 0; r < 4; r++) {
        int tok = p0 + w * 16 + quad * 4 + r;
        qkvbuf[(long)tok * 480 + col] = f2bf(acc[n][r] + bv);
      }
    }
  }
}

// ---------------------------------------------------------------------------
// Kernel B2: attention core via MFMA. One block per (window, head), 128 thr.
// ---------------------------------------------------------------------------
__global__ __launch_bounds__(128) void attn_core(unsigned short* __restrict__ qkvbuf,
                                                 const float* __restrict__ rpb,
                                                 int shift) {
  __shared__ unsigned short qs[64 * 40];   // bf16 [token][32], stride 40
  __shared__ unsigned short ks2[64 * 40];
  __shared__ unsigned short vT[32 * 68];   // bf16 [n][k], stride 68
  __shared__ float pb[64 * 68];            // scores / probs, stride 68
  __shared__ float bias_s[169];

  int tid = threadIdx.x;
  int bid = blockIdx.x;
  int w = bid / 5, h = bid - (bid / 5) * 5;
  int wid = w & 255;
  int wi = wid >> 4, wj = wid & 15;
  long base = (long)w * 49 * 480;

  for (int idx = tid; idx < 784; idx += 128) {
    int m = idx / 392;
    int r = idx - m * 392;
    int t = r >> 3, d4 = r & 7;
    ushort4 u = *(const ushort4*)&qkvbuf[base + (long)t * 480 + m * 160 + h * 32 + d4 * 4];
    unsigned short* dst = m ? ks2 : qs;
    *(ushort4*)&dst[t * 40 + d4 * 4] = u;
  }
  for (int idx = tid; idx < 392; idx += 128) {
    int t = idx >> 3, d4 = idx & 7;
    ushort4 u = *(const ushort4*)&qkvbuf[base + (long)t * 480 + 320 + h * 32 + d4 * 4];
    vT[(d4 * 4 + 0) * 68 + t] = u.x;
    vT[(d4 * 4 + 1) * 68 + t] = u.y;
    vT[(d4 * 4 + 2) * 68 + t] = u.z;
    vT[(d4 * 4 + 3) * 68 + t] = u.w;
  }
  for (int idx = tid; idx < 32 * 19; idx += 128) {
    int n = idx / 19, k2 = idx - n * 19;
    vT[n * 68 + 49 + k2] = 0;
  }
  for (int i = tid; i < 169; i += 128) bias_s[i] = rpb[i * 5 + h];
  __syncthreads();

  int wv = tid >> 6, lane = tid & 63, quad = lane >> 4, l16 = lane & 15;

  // ---- scores ----
#pragma unroll
  for (int mf2 = 0; mf2 < 2; mf2++) {
    int mf = wv * 2 + mf2;
    short8 a = *(const short8*)&qs[(mf * 16 + l16) * 40 + quad * 8];
    int iy[4], ix[4], ai[4], bi[4];
#pragma unroll
    for (int r = 0; r < 4; r++) {
      int i = mf * 16 + quad * 4 + r;
      iy[r] = i / 7; ix[r] = i - iy[r] * 7;
      if (shift) {
        int hri = wi * 7 + iy[r], wri = wj * 7 + ix[r];
        ai[r] = hri < 105 ? 0 : (hri < 109 ? 1 : 2);
        bi[r] = wri < 105 ? 0 : (wri < 109 ? 1 : 2);
      }
    }
#pragma unroll
    for (int nf = 0; nf < 4; nf++) {
      short8 b = *(const short8*)&ks2[(nf * 16 + l16) * 40 + quad * 8];
      floatx4 c = (floatx4){0.f, 0.f, 0.f, 0.f};
      c = __builtin_amdgcn_mfma_f32_16x16x32_bf16(a, b, c, 0, 0, 0);
      int jj = nf * 16 + l16;
      if (jj < 49) {
        int jy = jj / 7, jx = jj - jy * 7;
        int aj = 0, bj2 = 0;
        if (shift) {
          int hrj = wi * 7 + jy, wrj = wj * 7 + jx;
          aj = hrj < 105 ? 0 : (hrj < 109 ? 1 : 2);
          bj2 = wrj < 105 ? 0 : (wrj < 109 ? 1 : 2);
        }
#pragma unroll
        for (int r = 0; r < 4; r++) {
          int i = mf * 16 + quad * 4 + r;
          int rel = (iy[r] - jy + 6) * 13 + (ix[r] - jx + 6);
          rel = rel > 168 ? 168 : rel;
          float s = c[r] * 0.17677669529663687f + bias_s[rel];
          if (shift && (ai[r] != aj || bi[r] != bj2)) s -= 100.f;
          pb[i * 68 + jj] = s;
        }
      } else {
#pragma unroll
        for (int r = 0; r < 4; r++) {
          int i = mf * 16 + quad * 4 + r;
          pb[i * 68 + jj] = 0.f;
        }
      }
    }
  }
  __syncthreads();

  // ---- softmax rows 0..48 ----
  if (tid < 49) {
    float* row = &pb[tid * 68];
    float m = -1e30f;
    for (int j = 0; j < 49; j++) m = fmaxf(m, row[j]);
    float sum = 0.f;
    for (int j = 0; j < 49; j++) { float e = __expf(row[j] - m); row[j] = e; sum += e; }
    float inv = 1.f / sum;
    for (int j = 0; j < 49; j++) row[j] *= inv;
  }
  __syncthreads();

  // ---- PV ----
  short8 bv[2][2];
#pragma unroll
  for (int nf = 0; nf < 2; nf++)
#pragma unroll
    for (int ks = 0; ks < 2; ks++)
      bv[nf][ks] = *(const short8*)&vT[(nf * 16 + l16) * 68 + ks * 32 + quad * 8];

#pragma unroll
  for (int mf2 = 0; mf2 < 2; mf2++) {
    int mf = wv * 2 + mf2;
    short8 ap[2];
#pragma unroll
    for (int ks = 0; ks < 2; ks++) {
      const float* pr = &pb[(mf * 16 + l16) * 68 + ks * 32 + quad * 8];
      float4 plo = *(const float4*)pr;
      float4 phi = *(const float4*)(pr + 4);
      short8 av;
      av[0] = (short)f2bf(plo.x); av[1] = (short)f2bf(plo.y);
      av[2] = (short)f2bf(plo.z); av[3] = (short)f2bf(plo.w);
      av[4] = (short)f2bf(phi.x); av[5] = (short)f2bf(phi.y);
      av[6] = (short)f2bf(phi.z); av[7] = (short)f2bf(phi.w);
      ap[ks] = av;
    }
#pragma unroll
    for (int nf = 0; nf < 2; nf++) {
      floatx4 c = (floatx4){0.f, 0.f, 0.f, 0.f};
      c = __builtin_amdgcn_mfma_f32_16x16x32_bf16(ap[0], bv[nf][0], c, 0, 0, 0);
      c = __builtin_amdgcn_mfma_f32_16x16x32_bf16(ap[1], bv[nf][1], c, 0, 0, 0);
#pragma unroll
      for (int r = 0; r < 4; r++) {
        int row = mf * 16 + quad * 4 + r;
        if (row < 49)
          qkvbuf[base + (long)row * 480 + h * 32 + nf * 16 + l16] = f2bf(c[r]);
      }
    }
  }
}

// ---------------------------------------------------------------------------
// Kernel B3: proj via bf16 MFMA + residual scatter-add. 64 tokens/block.
// ---------------------------------------------------------------------------
__global__ __launch_bounds__(256) void proj_mfma(const unsigned short* __restrict__ qkvbuf,
                                                 const unsigned short* __restrict__ projf,
                                                 const float* __restrict__ projb,
                                                 float* __restrict__ x3,
                                                 int shift) {
  __shared__ unsigned short ao[64 * 168];
  __shared__ int spos[64];
  int tid = threadIdx.x;
  int p0 = blockIdx.x * 64;
  if (tid < 64) spos[tid] = token_pos(p0 + tid, shift);
  for (int idx = tid; idx < 10240; idx += 256) {
    int t = idx / 160, ch = idx - t * 160;
    ao[t * 168 + ch] = qkvbuf[(long)(p0 + t) * 480 + ch];
  }
  __syncthreads();

  int w = tid >> 6, lane = tid & 63, quad = lane >> 4, l16 = lane & 15;
  floatx4 acc[10];
#pragma unroll
  for (int n = 0; n < 10; n++) acc[n] = (floatx4){0.f, 0.f, 0.f, 0.f};
  for (int ks = 0; ks < 5; ks++) {
    short8 a = *(const short8*)&ao[(w * 16 + l16) * 168 + ks * 32 + quad * 8];
    const short8* bp = (const short8*)projf + (ks * 10) * 64 + lane;
#pragma unroll
    for (int n = 0; n < 10; n++)
      acc[n] = __builtin_amdgcn_mfma_f32_16x16x32_bf16(a, bp[n * 64], acc[n], 0, 0, 0);
  }
#pragma unroll
  for (int n = 0; n < 10; n++) {
    int col = n * 16 + l16;
    float bv = projb[orig_ch(col)];
#pragma unroll
    for (int r = 0; r < 4; r++) {
      int tl = w * 16 + quad * 4 + r;
      long a = (long)spos[tl] * DIM + col;
      x3[a] = x3[a] + acc[n][r] + bv;
    }
  }
}

// ---------------------------------------------------------------------------
// Kernel C: LN2 + MLP via bf16 MFMA. 32 tokens/block, 4 waves.
// R12: LDS cut 52224 -> 40960 B (4 blocks/CU): lnv/h1s share one buffer
// (lnv dead after fc1 MFMA loop; extra barrier), h1s stride 640 with XOR
// granule swizzle g' = g ^ (tok&7) instead of +8 padding (fc2 b128 reads
// spread 2-way over banks = free).
// ---------------------------------------------------------------------------
__global__ __launch_bounds__(256) void mlp_mfma(float* __restrict__ x3,
                                                const float* __restrict__ g,
                                                const float* __restrict__ bb,
                                                const unsigned short* __restrict__ w1f,
                                                const float* __restrict__ b1,
                                                const unsigned short* __restrict__ w2f,
                                                const float* __restrict__ b2) {
  __shared__ __align__(16) unsigned short smem[32 * 640];  // 40960 B union
  unsigned short* lnv = smem;                              // [32][168] while live

  int tid = threadIdx.x;
  long p0 = (long)blockIdx.x * 32;

  // ---- LN2: 8 threads per token ----
  {
    int t = tid >> 3, sub = tid & 7;
    const float* row = x3 + (p0 + t) * 160 + sub * 20;
    float xv[20];
    float s1 = 0.f, s2 = 0.f;
#pragma unroll
    for (int m = 0; m < 20; m++) { float v = row[m]; xv[m] = v; s1 += v; s2 += v * v; }
#pragma unroll
    for (int m = 1; m < 8; m <<= 1) { s1 += __shfl_xor(s1, m); s2 += __shfl_xor(s2, m); }
    float mu = s1 * (1.f / 160.f);
    float rs = rsqrtf(s2 * (1.f / 160.f) - mu * mu + 1e-5f);
#pragma unroll
    for (int m = 0; m < 20; m++) {
      int c = sub * 20 + m;
      int oc = orig_ch(c);
      lnv[t * 168 + c] = f2bf((xv[m] - mu) * rs * g[oc] + bb[oc]);
    }
  }
  __syncthreads();

  int w = tid >> 6, lane = tid & 63, quad = lane >> 4, l16 = lane & 15;

  // ---- fc1: wave w -> cols [w*160, w*160+160) ----
  floatx4 acc[2][10];
#pragma unroll
  for (int mf = 0; mf < 2; mf++)
#pragma unroll
    for (int n = 0; n < 10; n++) acc[mf][n] = (floatx4){0.f, 0.f, 0.f, 0.f};

  for (int ks = 0; ks < 5; ks++) {
    short8 a0 = *(const short8*)&lnv[l16 * 168 + ks * 32 + quad * 8];
    short8 a1 = *(const short8*)&lnv[(16 + l16) * 168 + ks * 32 + quad * 8];
    const short8* bp = (const short8*)w1f + (ks * 40 + w * 10) * 64 + lane;
#pragma unroll
    for (int n = 0; n < 10; n++) {
      short8 bf = bp[n * 64];
      acc[0][n] = __builtin_amdgcn_mfma_f32_16x16x32_bf16(a0, bf, acc[0][n], 0, 0, 0);
      acc[1][n] = __builtin_amdgcn_mfma_f32_16x16x32_bf16(a1, bf, acc[1][n], 0, 0, 0);
    }
  }
  __syncthreads();  // all lnv reads done before h1s overwrites the buffer

  // fc1 epilogue: bias + gelu -> swizzled h1s (stride 640, granule XOR tok&7)
#pragma unroll
  for (int mf = 0; mf < 2; mf++)
#pragma unroll
    for (int n = 0; n < 10; n++) {
      int col = w * 160 + n * 16 + l16;
      int gidx = col >> 3, j = col & 7;
      float bv = b1[col];
#pragma unroll
      for (int r = 0; r < 4; r++) {
        int tok = mf * 16 + quad * 4 + r;
        int gs = gidx ^ (tok & 7);
        smem[tok * 640 + gs * 8 + j] = f2bf(gelu_f(acc[mf][n][r] + bv));
      }
    }
  __syncthreads();

  // ---- fc2: wave w -> M-frag (w&1), N-frags [(w>>1)*5 .. +5), full K ----
  int mf = w & 1, nb = (w >> 1) * 5;
  int m = mf * 16 + l16;
  floatx4 acc2[5];
#pragma unroll
  for (int n = 0; n < 5; n++) acc2[n] = (floatx4){0.f, 0.f, 0.f, 0.f};
  for (int ks = 0; ks < 20; ks++) {
    int gs = (ks * 4 + quad) ^ (m & 7);
    short8 a = *(const short8*)&smem[m * 640 + gs * 8];
    const short8* bp = (const short8*)w2f + (ks * 10 + nb) * 64 + lane;
#pragma unroll
    for (int n = 0; n < 5; n++)
      acc2[n] = __builtin_amdgcn_mfma_f32_16x16x32_bf16(a, bp[n * 64], acc2[n], 0, 0, 0);
  }

  // residual + bias writeout
#pragma unroll
  for (int n = 0; n < 5; n++) {
    int col = (nb + n) * 16 + l16;
    float bv = b2[orig_ch(col)];
#pragma unroll
    for (int r = 0; r < 4; r++) {
      int tok = mf * 16 + quad * 4 + r;
      long a = (p0 + tok) * 160 + col;
      x3[a] = x3[a] + acc2[n][r] + bv;
    }
  }
}

// ---------------------------------------------------------------------------
// Kernel D: lin via bf16 MFMA -> plane-major yp [144][NPOS].
// ---------------------------------------------------------------------------
__global__ __launch_bounds__(256) void lin_mfma(const float* __restrict__ x3,
                                                const unsigned short* __restrict__ linf,
                                                const float* __restrict__ linb,
                                                float* __restrict__ yp) {
  __shared__ unsigned short xs[64 * 168];
  int tid = threadIdx.x;
  int p0 = blockIdx.x * 64;

  for (int idx = tid; idx < 5120; idx += 256) {
    int t = idx / 80, c2 = idx - t * 80;
    float2 v = *(const float2*)&x3[((long)(p0 + t)) * 160 + c2 * 2];
    *(ushort2*)&xs[t * 168 + c2 * 2] = make_ushort2(f2bf(v.x), f2bf(v.y));
  }
  __syncthreads();

  int w = tid >> 6, lane = tid & 63, quad = lane >> 4, l16 = lane & 15;
  floatx4 acc[9];
#pragma unroll
  for (int n = 0; n < 9; n++) acc[n] = (floatx4){0.f, 0.f, 0.f, 0.f};
  for (int ks = 0; ks < 5; ks++) {
    short8 a = *(const short8*)&xs[(w * 16 + l16) * 168 + ks * 32 + quad * 8];
    const short8* bp = (const short8*)linf + (ks * 9) * 64 + lane;
#pragma unroll
    for (int n = 0; n < 9; n++)
      acc[n] = __builtin_amdgcn_mfma_f32_16x16x32_bf16(a, bp[n * 64], acc[n], 0, 0, 0);
  }
#pragma unroll
  for (int n = 0; n < 9; n++) {
    int col = n * 16 + l16;
    float bv = linb[col];
    float4 o = make_float4(acc[n][0] + bv, acc[n][1] + bv, acc[n][2] + bv, acc[n][3] + bv);
    *(float4*)&yp[(long)col * NPOS + p0 + w * 16 + quad * 4] = o;
  }
}

// ---------------------------------------------------------------------------
// Kernel E: synthesis conv, sliding-window register blocking.
// ---------------------------------------------------------------------------
__global__ __launch_bounds__(256) void syn_kernel(const float* __restrict__ yp,
                                                  const float* __restrict__ fsyn,
                                                  float* __restrict__ yt) {
  __shared__ float tileS[24 * 120];
  __shared__ float fsl[729];
  int tid = threadIdx.x;
  int blk = blockIdx.x;
  int tile = blk % 7;
  int c = (blk / 7) % 16;
  int b = blk / 112;
  int ty0 = tile * 16;

  for (int i = tid; i < 729; i += 256) fsl[i] = fsyn[i];

  int ty = tid >> 4, txg = tid & 15;
  float acc[7];
#pragma unroll
  for (int w = 0; w < 7; w++) acc[w] = 0.f;

  for (int k = 0; k < 9; k++) {
    const float* plane = yp + (long)(k * 16 + c) * NPOS + (long)b * HH * WW;
    __syncthreads();
    for (int idx = tid; idx < 2880; idx += 256) {
      int ly = idx / 120, lx = idx - ly * 120;
      int gy = ty0 + ly - 4, gx = lx - 4;
      float v = 0.f;
      if (gy >= 0 && gy < HH && gx >= 0 && gx < WW) v = plane[gy * WW + gx];
      tileS[idx] = v;
    }
    __syncthreads();

#pragma unroll
    for (int ky = 0; ky < 9; ky++) {
      const float* row = &tileS[(ty + ky) * 120 + txg * 7];
      float rr[15];
#pragma unroll
      for (int i = 0; i < 15; i++) rr[i] = row[i];
      const float* fk = &fsl[k * 81 + ky * 9];
#pragma unroll
      for (int kx = 0; kx < 9; kx++) {
        float f = fk[kx];
#pragma unroll
        for (int w = 0; w < 7; w++) acc[w] += rr[kx + w] * f;
      }
    }
  }

  long obase = (long)c * NPOS + ((long)b * HH + (ty0 + ty)) * WW + txg * 7;
#pragma unroll
  for (int w = 0; w < 7; w++) yt[obase + w] = acc[w];
}

// ---------------------------------------------------------------------------
// Kernel F: final 1x1 conv from plane-major inputs -> out [B,16,H,W]
// ---------------------------------------------------------------------------
__global__ __launch_bounds__(256) void final_kernel(const float* __restrict__ yt,
                                                    const float* __restrict__ yp,
                                                    const float* __restrict__ convw,
                                                    const float* __restrict__ convb,
                                                    float* __restrict__ out) {
  long pos = (long)blockIdx.x * 256 + threadIdx.x;
  if (pos >= NPOS) return;
  int b = (int)(pos / (HH * WW));
  int hw = (int)(pos - (long)b * HH * WW);

  float acc[16];
#pragma unroll
  for (int co = 0; co < 16; co++) acc[co] = convb[co];
  for (int c = 0; c < 16; c++) {
    float v = yt[(long)c * NPOS + pos];
#pragma unroll
    for (int co = 0; co < 16; co++) acc[co] += v * convw[co * 160 + c];
  }
  for (int j = 0; j < 144; j++) {
    float v = yp[(long)j * NPOS + pos];
#pragma unroll
    for (int co = 0; co < 16; co++) acc[co] += v * convw[co * 160 + 16 + j];
  }
#pragma unroll
  for (int co = 0; co < 16; co++)
    out[(((long)b * 16 + co) * HH * WW) + hw] = acc[co];
}

// ---------------------------------------------------------------------------
extern "C" void kernel_launch(void* const* d_in, const int* in_sizes, int n_in,
                              void* d_out, int out_size, void* d_ws, size_t ws_size,
                              hipStream_t stream) {
  const float* x     = (const float*)d_in[0];
  const float* fana  = (const float*)d_in[1];
  const float* fsyn  = (const float*)d_in[2];
  const float* ln1g  = (const float*)d_in[3];
  const float* ln1b  = (const float*)d_in[4];
  const float* qkvw  = (const float*)d_in[5];
  const float* qkvb  = (const float*)d_in[6];
  const float* projw = (const float*)d_in[7];
  const float* projb = (const float*)d_in[8];
  const float* rpb   = (const float*)d_in[9];
  const float* ln2g  = (const float*)d_in[10];
  const float* ln2b  = (const float*)d_in[11];
  const float* w1    = (const float*)d_in[12];
  const float* b1    = (const float*)d_in[13];
  const float* w2    = (const float*)d_in[14];
  const float* b2    = (const float*)d_in[15];
  const float* linw  = (const float*)d_in[16];
  const float* linb  = (const float*)d_in[17];
  const float* convw = (const float*)d_in[18];
  const float* convb = (const float*)d_in[19];
  float* out = (float*)d_out;

  char* ws = (char*)d_ws;
  float* x3 = (float*)ws;                           // live whole run
  char* region2 = ws + 64225280;                    // time-shared:
  unsigned short* qkvbuf = (unsigned short*)region2;           // bf16 [NPOS x 480]
  unsigned short* packs  = (unsigned short*)(region2 + 96337920);
  unsigned short* qkvf = packs;
  unsigned short* projf = packs + 76800;
  unsigned short* w1f   = packs + 102400;
  unsigned short* w2f   = packs + 204800;
  unsigned short* linf  = packs + 307200;
  float* yp = (float*)region2;
  float* yt = (float*)ws;

  ana_kernel<<<BB * 49, 256, 0, stream>>>(x, fana, x3);
  pack1_kernel<<<90, 256, 0, stream>>>(linw, linf, 9, 144, 23040, 1, 0);
  for (int i = 0; i < 2; i++) {
    int shift = i ? (WIN / 2) : 0;
    pack4_kernel<<<1200, 256, 0, stream>>>(qkvw + i * 76800, projw + i * 25600,
                                           w1 + i * 102400, w2 + i * 102400,
                                           qkvf, projf, w1f, w2f);
    qkv_mfma<<<NPOS / 64, 256, 0, stream>>>(x3, ln1g + i * 160, ln1b + i * 160,
                                            qkvf, qkvb + i * 480, qkvbuf, shift);
    attn_core<<<BB * NWIN * HEADS, 128, 0, stream>>>(qkvbuf, rpb + i * 169 * 5, shift);
    proj_mfma<<<NPOS / 64, 256, 0, stream>>>(qkvbuf, projf, projb + i * 160, x3, shift);
    mlp_mfma<<<NPOS / 32, 256, 0, stream>>>(x3, ln2g + i * 160, ln2b + i * 160,
                                            w1f, b1 + i * 640, w2f, b2 + i * 160);
  }
  lin_mfma<<<NPOS / 64, 256, 0, stream>>>(x3, linf, linb, yp);
  syn_kernel<<<BB * 16 * 7, 256, 0, stream>>>(yp, fsyn, yt);
  final_kernel<<<(NPOS + 255) / 256, 256, 0, stream>>>(yt, yp, convw, convb, out);
}

// Round 15
// 1021.037 us; speedup vs baseline: 1.0729x; 1.0729x over previous
//
#include <hip/hip_runtime.h>
#include <hip/hip_bf16.h>
#include <math.h>

#define BB 8
#define CC 16
#define HH 112
#define WW 112
#define KK 9
#define FS 9
#define WIN 7
#define DIM 160
#define HEADS 5
#define HDIM 32
#define MLPD 640
#define NWIN 256          // (112/7)^2
#define NPOS (BB*HH*WW)   // 100352

typedef __attribute__((ext_vector_type(8))) short short8;
typedef __attribute__((ext_vector_type(4))) float floatx4;

__device__ __forceinline__ unsigned short f2bf(float f) {
  union { float f; unsigned u; } v; v.f = f;
  unsigned r = v.u + 0x7fffu + ((v.u >> 16) & 1u);
  return (unsigned short)(r >> 16);
}
__device__ __forceinline__ float bf2f(unsigned short u) {
  union { unsigned u; float f; } v; v.u = ((unsigned)u) << 16;
  return v.f;
}
// gelu tanh-approx, exp-based (same formula as jax.nn.gelu, no libm tanh)
__device__ __forceinline__ float gelu_f(float a) {
  float z = 0.7978845608028654f * (a + 0.044715f * a * a * a);
  return a * __builtin_amdgcn_rcpf(1.f + __expf(-2.f * z));
}
// x3 uses internal channel order ch' = c*10 + k (k=0..8 subbands, 9 = relu skip).
__device__ __forceinline__ int orig_ch(int ch) {
  int c = ch / 10, k = ch - c * 10;
  return (k < 9) ? k * 16 + c : 144 + c;
}

// ---------------------------------------------------------------------------
// Kernel A: relu + analysis filter bank -> x3 (permuted channels).
// 16x16 tile, grid 392, ONE THREAD owns each position's full 640B channel row
// (the only write scheme measured clean — wave/block splits caused ~12x RMW).
// 4-channel grouping: 13 LDS reads feed 36 FMAs (ana was LDS-issue-bound).
// ---------------------------------------------------------------------------
__global__ __launch_bounds__(256) void ana_kernel(const float* __restrict__ x,
                                                  const float* __restrict__ fana,
                                                  float* __restrict__ x3) {
  __shared__ float tileS[16 * 576];  // 16 ch x 24x24
  __shared__ float fs[729];
  int tid = threadIdx.x;
  int blk = blockIdx.x;
  int b = blk / 49;
  int tile = blk - b * 49;
  int y0 = (tile / 7) * 16, x0 = (tile % 7) * 16;

  for (int i = tid; i < 729; i += 256) fs[i] = fana[i];
  for (int idx = tid; idx < 9216; idx += 256) {
    int c = idx / 576, r = idx - c * 576;
    int ly = r / 24, lx = r - ly * 24;
    int gy = y0 + ly - 4, gx = x0 + lx - 4;
    float v = 0.f;
    if (gy >= 0 && gy < HH && gx >= 0 && gx < WW)
      v = fmaxf(x[(((long)b * CC + c) * HH + gy) * WW + gx], 0.f);
    tileS[idx] = v;
  }
  __syncthreads();

  int ty = tid >> 4, tx = tid & 15;
  long obase = (((long)b * HH + (y0 + ty)) * WW + (x0 + tx)) * DIM;
  for (int cg = 0; cg < 4; cg++) {
    float acc[4][9];
#pragma unroll
    for (int cl = 0; cl < 4; cl++)
#pragma unroll
      for (int k = 0; k < 9; k++) acc[cl][k] = 0.f;
    const float* ts0 = &tileS[(cg * 4 + 0) * 576];
    const float* ts1 = &tileS[(cg * 4 + 1) * 576];
    const float* ts2 = &tileS[(cg * 4 + 2) * 576];
    const float* ts3 = &tileS[(cg * 4 + 3) * 576];
    for (int ky = 0; ky < 9; ky++) {
      for (int kx = 0; kx < 9; kx++) {
        int toff = (ty + ky) * 24 + (tx + kx);
        float f[9];
#pragma unroll
        for (int k = 0; k < 9; k++) f[k] = fs[k * 81 + ky * 9 + kx];
        float v0 = ts0[toff], v1 = ts1[toff], v2 = ts2[toff], v3 = ts3[toff];
#pragma unroll
        for (int k = 0; k < 9; k++) {
          acc[0][k] += v0 * f[k];
          acc[1][k] += v1 * f[k];
          acc[2][k] += v2 * f[k];
          acc[3][k] += v3 * f[k];
        }
      }
    }
    int center = (ty + 4) * 24 + (tx + 4);
    const float* tsp[4] = {ts0, ts1, ts2, ts3};
#pragma unroll
    for (int cl = 0; cl < 4; cl++) {
      int c = cg * 4 + cl;
      float skip = tsp[cl][center];
      float2* dst = (float2*)&x3[obase + c * 10];
      dst[0] = make_float2(acc[cl][0], acc[cl][1]);
      dst[1] = make_float2(acc[cl][2], acc[cl][3]);
      dst[2] = make_float2(acc[cl][4], acc[cl][5]);
      dst[3] = make_float2(acc[cl][6], acc[cl][7]);
      dst[4] = make_float2(acc[cl][8], skip);
    }
  }
}

// ---------------------------------------------------------------------------
// token_pos: window-ordered flat token p -> source position in [B,H,W]
// ---------------------------------------------------------------------------
__device__ __forceinline__ int token_pos(int p, int shift) {
  int w = p / 49;
  int t = p - w * 49;
  int b = w >> 8;
  int wid = w & 255;
  int wi = wid >> 4, wj = wid & 15;
  int iy = t / 7, ix = t - (t / 7) * 7;
  int hy = (wi * 7 + iy + shift) % HH;
  int wx = (wj * 7 + ix + shift) % WW;
  return (b * HH + hy) * WW + wx;
}

// ---------------------------------------------------------------------------
// Weight packing: fp32 [K x ncols] -> bf16 MFMA B-fragment-major layout.
// ---------------------------------------------------------------------------
__device__ __forceinline__ void pack_one(const float* __restrict__ src,
                                         unsigned short* __restrict__ dst,
                                         int nfcnt, int ncols, int nelems,
                                         int permK, int permN, int idx) {
  if (idx >= nelems) return;
  int j = idx & 7;
  int lane = (idx >> 3) & 63;
  int t = idx >> 9;
  int nf = t % nfcnt, ks = t / nfcnt;
  int k = ks * 32 + (lane >> 4) * 8 + j;
  int n = nf * 16 + (lane & 15);
  if (permK) k = orig_ch(k);
  if (permN) n = orig_ch(n);
  dst[idx] = f2bf(src[k * ncols + n]);
}

__global__ __launch_bounds__(256) void pack4_kernel(const float* __restrict__ qkvw,
                                                    const float* __restrict__ projw,
                                                    const float* __restrict__ w1,
                                                    const float* __restrict__ w2,
                                                    unsigned short* __restrict__ qkvf,
                                                    unsigned short* __restrict__ projf,
                                                    unsigned short* __restrict__ w1f,
                                                    unsigned short* __restrict__ w2f) {
  int blk = blockIdx.x, tid = threadIdx.x;
  if (blk < 300)      pack_one(qkvw,  qkvf,  30, 480, 76800,  1, 0, blk * 256 + tid);
  else if (blk < 400) pack_one(projw, projf, 10, 160, 25600,  0, 1, (blk - 300) * 256 + tid);
  else if (blk < 800) pack_one(w1,    w1f,   40, 640, 102400, 1, 0, (blk - 400) * 256 + tid);
  else                pack_one(w2,    w2f,   10, 160, 102400, 0, 1, (blk - 800) * 256 + tid);
}

__global__ __launch_bounds__(256) void pack1_kernel(const float* __restrict__ src,
                                                    unsigned short* __restrict__ dst,
                                                    int nfcnt, int ncols, int nelems,
                                                    int permK, int permN) {
  pack_one(src, dst, nfcnt, ncols, nelems, permK, permN, blockIdx.x * 256 + threadIdx.x);
}

// ---------------------------------------------------------------------------
// Kernel B1: LN1 + qkv GEMM via bf16 MFMA. 64 tokens/block (window-ordered).
// ---------------------------------------------------------------------------
__global__ __launch_bounds__(256) void qkv_mfma(const float* __restrict__ x3,
                                                const float* __restrict__ g,
                                                const float* __restrict__ bb,
                                                const unsigned short* __restrict__ qkvf,
                                                const float* __restrict__ qkvb,
                                                unsigned short* __restrict__ qkvbuf,
                                                int shift) {
  __shared__ unsigned short lnv[64 * 168];  // bf16, row stride 168

  int tid = threadIdx.x;
  int p0 = blockIdx.x * 64;

  {
    int t = tid >> 2, sub = tid & 3;
    int pos = token_pos(p0 + t, shift);
    const float* row = x3 + (long)pos * 160 + sub * 40;
    float xv[40];
    float s1 = 0.f, s2 = 0.f;
#pragma unroll
    for (int m = 0; m < 40; m++) { float v = row[m]; xv[m] = v; s1 += v; s2 += v * v; }
    s1 += __shfl_xor(s1, 1); s2 += __shfl_xor(s2, 1);
    s1 += __shfl_xor(s1, 2); s2 += __shfl_xor(s2, 2);
    float mu = s1 * (1.f / 160.f);
    float rs = rsqrtf(s2 * (1.f / 160.f) - mu * mu + 1e-5f);
#pragma unroll
    for (int m = 0; m < 40; m++) {
      int c = sub * 40 + m;
      int oc = orig_ch(c);
      lnv[t * 168 + c] = f2bf((xv[m] - mu) * rs * g[oc] + bb[oc]);
    }
  }
  __syncthreads();

  int w = tid >> 6, lane = tid & 63, quad = lane >> 4, l16 = lane & 15;

#pragma unroll
  for (int half = 0; half < 2; half++) {
    floatx4 acc[15];
#pragma unroll
    for (int n = 0; n < 15; n++) acc[n] = (floatx4){0.f, 0.f, 0.f, 0.f};
    for (int ks = 0; ks < 5; ks++) {
      short8 a = *(const short8*)&lnv[(w * 16 + l16) * 168 + ks * 32 + quad * 8];
      const short8* bp = (const short8*)qkvf + (ks * 30 + half * 15) * 64 + lane;
#pragma unroll
      for (int n = 0; n < 15; n++)
        acc[n] = __builtin_amdgcn_mfma_f32_16x16x32_bf16(a, bp[n * 64], acc[n], 0, 0, 0);
    }
#pragma unroll
    for (int n = 0; n < 15; n++) {
      int col = (half * 15 + n) * 16 + l16;
      float bv = qkvb[col];
#pragma unroll
      for (int r = 0; r < 4; r++) {
        int tok = p0 + w * 16 + quad * 4 + r;
        qkvbuf[(long)tok * 480 + col] = f2bf(acc[n][r] + bv);
      }
    }
  }
}

// ---------------------------------------------------------------------------
// Kernel B2: attention core via MFMA. One block per (window, head), 128 thr.
// ---------------------------------------------------------------------------
__global__ __launch_bounds__(128) void attn_core(unsigned short* __restrict__ qkvbuf,
                                                 const float* __restrict__ rpb,
                                                 int shift) {
  __shared__ unsigned short qs[64 * 40];   // bf16 [token][32], stride 40
  __shared__ unsigned short ks2[64 * 40];
  __shared__ unsigned short vT[32 * 68];   // bf16 [n][k], stride 68
  __shared__ float pb[64 * 68];            // scores / probs, stride 68
  __shared__ float bias_s[169];

  int tid = threadIdx.x;
  int bid = blockIdx.x;
  int w = bid / 5, h = bid - (bid / 5) * 5;
  int wid = w & 255;
  int wi = wid >> 4, wj = wid & 15;
  long base = (long)w * 49 * 480;

  for (int idx = tid; idx < 784; idx += 128) {
    int m = idx / 392;
    int r = idx - m * 392;
    int t = r >> 3, d4 = r & 7;
    ushort4 u = *(const ushort4*)&qkvbuf[base + (long)t * 480 + m * 160 + h * 32 + d4 * 4];
    unsigned short* dst = m ? ks2 : qs;
    *(ushort4*)&dst[t * 40 + d4 * 4] = u;
  }
  for (int idx = tid; idx < 392; idx += 128) {
    int t = idx >> 3, d4 = idx & 7;
    ushort4 u = *(const ushort4*)&qkvbuf[base + (long)t * 480 + 320 + h * 32 + d4 * 4];
    vT[(d4 * 4 + 0) * 68 + t] = u.x;
    vT[(d4 * 4 + 1) * 68 + t] = u.y;
    vT[(d4 * 4 + 2) * 68 + t] = u.z;
    vT[(d4 * 4 + 3) * 68 + t] = u.w;
  }
  for (int idx = tid; idx < 32 * 19; idx += 128) {
    int n = idx / 19, k2 = idx - n * 19;
    vT[n * 68 + 49 + k2] = 0;
  }
  for (int i = tid; i < 169; i += 128) bias_s[i] = rpb[i * 5 + h];
  __syncthreads();

  int wv = tid >> 6, lane = tid & 63, quad = lane >> 4, l16 = lane & 15;

  // ---- scores ----
#pragma unroll
  for (int mf2 = 0; mf2 < 2; mf2++) {
    int mf = wv * 2 + mf2;
    short8 a = *(const short8*)&qs[(mf * 16 + l16) * 40 + quad * 8];
    int iy[4], ix[4], ai[4], bi[4];
#pragma unroll
    for (int r = 0; r < 4; r++) {
      int i = mf * 16 + quad * 4 + r;
      iy[r] = i / 7; ix[r] = i - iy[r] * 7;
      if (shift) {
        int hri = wi * 7 + iy[r], wri = wj * 7 + ix[r];
        ai[r] = hri < 105 ? 0 : (hri < 109 ? 1 : 2);
        bi[r] = wri < 105 ? 0 : (wri < 109 ? 1 : 2);
      }
    }
#pragma unroll
    for (int nf = 0; nf < 4; nf++) {
      short8 b = *(const short8*)&ks2[(nf * 16 + l16) * 40 + quad * 8];
      floatx4 c = (floatx4){0.f, 0.f, 0.f, 0.f};
      c = __builtin_amdgcn_mfma_f32_16x16x32_bf16(a, b, c, 0, 0, 0);
      int jj = nf * 16 + l16;
      if (jj < 49) {
        int jy = jj / 7, jx = jj - jy * 7;
        int aj = 0, bj2 = 0;
        if (shift) {
          int hrj = wi * 7 + jy, wrj = wj * 7 + jx;
          aj = hrj < 105 ? 0 : (hrj < 109 ? 1 : 2);
          bj2 = wrj < 105 ? 0 : (wrj < 109 ? 1 : 2);
        }
#pragma unroll
        for (int r = 0; r < 4; r++) {
          int i = mf * 16 + quad * 4 + r;
          int rel = (iy[r] - jy + 6) * 13 + (ix[r] - jx + 6);
          rel = rel > 168 ? 168 : rel;
          float s = c[r] * 0.17677669529663687f + bias_s[rel];
          if (shift && (ai[r] != aj || bi[r] != bj2)) s -= 100.f;
          pb[i * 68 + jj] = s;
        }
      } else {
#pragma unroll
        for (int r = 0; r < 4; r++) {
          int i = mf * 16 + quad * 4 + r;
          pb[i * 68 + jj] = 0.f;
        }
      }
    }
  }
  __syncthreads();

  // ---- softmax rows 0..48 ----
  if (tid < 49) {
    float* row = &pb[tid * 68];
    float m = -1e30f;
    for (int j = 0; j < 49; j++) m = fmaxf(m, row[j]);
    float sum = 0.f;
    for (int j = 0; j < 49; j++) { float e = __expf(row[j] - m); row[j] = e; sum += e; }
    float inv = 1.f / sum;
    for (int j = 0; j < 49; j++) row[j] *= inv;
  }
  __syncthreads();

  // ---- PV ----
  short8 bv[2][2];
#pragma unroll
  for (int nf = 0; nf < 2; nf++)
#pragma unroll
    for (int ks = 0; ks < 2; ks++)
      bv[nf][ks] = *(const short8*)&vT[(nf * 16 + l16) * 68 + ks * 32 + quad * 8];

#pragma unroll
  for (int mf2 = 0; mf2 < 2; mf2++) {
    int mf = wv * 2 + mf2;
    short8 ap[2];
#pragma unroll
    for (int ks = 0; ks < 2; ks++) {
      const float* pr = &pb[(mf * 16 + l16) * 68 + ks * 32 + quad * 8];
      float4 plo = *(const float4*)pr;
      float4 phi = *(const float4*)(pr + 4);
      short8 av;
      av[0] = (short)f2bf(plo.x); av[1] = (short)f2bf(plo.y);
      av[2] = (short)f2bf(plo.z); av[3] = (short)f2bf(plo.w);
      av[4] = (short)f2bf(phi.x); av[5] = (short)f2bf(phi.y);
      av[6] = (short)f2bf(phi.z); av[7] = (short)f2bf(phi.w);
      ap[ks] = av;
    }
#pragma unroll
    for (int nf = 0; nf < 2; nf++) {
      floatx4 c = (floatx4){0.f, 0.f, 0.f, 0.f};
      c = __builtin_amdgcn_mfma_f32_16x16x32_bf16(ap[0], bv[nf][0], c, 0, 0, 0);
      c = __builtin_amdgcn_mfma_f32_16x16x32_bf16(ap[1], bv[nf][1], c, 0, 0, 0);
#pragma unroll
      for (int r = 0; r < 4; r++) {
        int row = mf * 16 + quad * 4 + r;
        if (row < 49)
          qkvbuf[base + (long)row * 480 + h * 32 + nf * 16 + l16] = f2bf(c[r]);
      }
    }
  }
}

// ---------------------------------------------------------------------------
// Kernel B3: proj via bf16 MFMA + residual scatter-add. 64 tokens/block.
// ---------------------------------------------------------------------------
__global__ __launch_bounds__(256) void proj_mfma(const unsigned short* __restrict__ qkvbuf,
                                                 const unsigned short* __restrict__ projf,
                                                 const float* __restrict__ projb,
                                                 float* __restrict__ x3,
                                                 int shift) {
  __shared__ unsigned short ao[64 * 168];
  __shared__ int spos[64];
  int tid = threadIdx.x;
  int p0 = blockIdx.x * 64;
  if (tid < 64) spos[tid] = token_pos(p0 + tid, shift);
  for (int idx = tid; idx < 10240; idx += 256) {
    int t = idx / 160, ch = idx - t * 160;
    ao[t * 168 + ch] = qkvbuf[(long)(p0 + t) * 480 + ch];
  }
  __syncthreads();

  int w = tid >> 6, lane = tid & 63, quad = lane >> 4, l16 = lane & 15;
  floatx4 acc[10];
#pragma unroll
  for (int n = 0; n < 10; n++) acc[n] = (floatx4){0.f, 0.f, 0.f, 0.f};
  for (int ks = 0; ks < 5; ks++) {
    short8 a = *(const short8*)&ao[(w * 16 + l16) * 168 + ks * 32 + quad * 8];
    const short8* bp = (const short8*)projf + (ks * 10) * 64 + lane;
#pragma unroll
    for (int n = 0; n < 10; n++)
      acc[n] = __builtin_amdgcn_mfma_f32_16x16x32_bf16(a, bp[n * 64], acc[n], 0, 0, 0);
  }
#pragma unroll
  for (int n = 0; n < 10; n++) {
    int col = n * 16 + l16;
    float bv = projb[orig_ch(col)];
#pragma unroll
    for (int r = 0; r < 4; r++) {
      int tl = w * 16 + quad * 4 + r;
      long a = (long)spos[tl] * DIM + col;
      x3[a] = x3[a] + acc[n][r] + bv;
    }
  }
}

// ---------------------------------------------------------------------------
// Kernel C: LN2 + MLP via bf16 MFMA. 32 tokens/block, 4 waves.
// ---------------------------------------------------------------------------
__global__ __launch_bounds__(256) void mlp_mfma(float* __restrict__ x3,
                                                const float* __restrict__ g,
                                                const float* __restrict__ bb,
                                                const unsigned short* __restrict__ w1f,
                                                const float* __restrict__ b1,
                                                const unsigned short* __restrict__ w2f,
                                                const float* __restrict__ b2) {
  __shared__ unsigned short lnv[32 * 168];
  __shared__ unsigned short h1s[32 * 648];

  int tid = threadIdx.x;
  long p0 = (long)blockIdx.x * 32;

  {
    int t = tid >> 3, sub = tid & 7;
    const float* row = x3 + (p0 + t) * 160 + sub * 20;
    float xv[20];
    float s1 = 0.f, s2 = 0.f;
#pragma unroll
    for (int m = 0; m < 20; m++) { float v = row[m]; xv[m] = v; s1 += v; s2 += v * v; }
#pragma unroll
    for (int m = 1; m < 8; m <<= 1) { s1 += __shfl_xor(s1, m); s2 += __shfl_xor(s2, m); }
    float mu = s1 * (1.f / 160.f);
    float rs = rsqrtf(s2 * (1.f / 160.f) - mu * mu + 1e-5f);
#pragma unroll
    for (int m = 0; m < 20; m++) {
      int c = sub * 20 + m;
      int oc = orig_ch(c);
      lnv[t * 168 + c] = f2bf((xv[m] - mu) * rs * g[oc] + bb[oc]);
    }
  }
  __syncthreads();

  int w = tid >> 6, lane = tid & 63, quad = lane >> 4, l16 = lane & 15;

  floatx4 acc[2][10];
#pragma unroll
  for (int mf = 0; mf < 2; mf++)
#pragma unroll
    for (int n = 0; n < 10; n++) acc[mf][n] = (floatx4){0.f, 0.f, 0.f, 0.f};

  for (int ks = 0; ks < 5; ks++) {
    short8 a0 = *(const short8*)&lnv[l16 * 168 + ks * 32 + quad * 8];
    short8 a1 = *(const short8*)&lnv[(16 + l16) * 168 + ks * 32 + quad * 8];
    const short8* bp = (const short8*)w1f + (ks * 40 + w * 10) * 64 + lane;
#pragma unroll
    for (int n = 0; n < 10; n++) {
      short8 bf = bp[n * 64];
      acc[0][n] = __builtin_amdgcn_mfma_f32_16x16x32_bf16(a0, bf, acc[0][n], 0, 0, 0);
      acc[1][n] = __builtin_amdgcn_mfma_f32_16x16x32_bf16(a1, bf, acc[1][n], 0, 0, 0);
    }
  }

#pragma unroll
  for (int mf = 0; mf < 2; mf++)
#pragma unroll
    for (int n = 0; n < 10; n++) {
      int col = w * 160 + n * 16 + l16;
      float bv = b1[col];
#pragma unroll
      for (int r = 0; r < 4; r++) {
        int tok = mf * 16 + quad * 4 + r;
        h1s[tok * 648 + col] = f2bf(gelu_f(acc[mf][n][r] + bv));
      }
    }
  __syncthreads();

  int mf = w & 1, nb = (w >> 1) * 5;
  floatx4 acc2[5];
#pragma unroll
  for (int n = 0; n < 5; n++) acc2[n] = (floatx4){0.f, 0.f, 0.f, 0.f};
  for (int ks = 0; ks < 20; ks++) {
    short8 a = *(const short8*)&h1s[(mf * 16 + l16) * 648 + ks * 32 + quad * 8];
    const short8* bp = (const short8*)w2f + (ks * 10 + nb) * 64 + lane;
#pragma unroll
    for (int n = 0; n < 5; n++)
      acc2[n] = __builtin_amdgcn_mfma_f32_16x16x32_bf16(a, bp[n * 64], acc2[n], 0, 0, 0);
  }

#pragma unroll
  for (int n = 0; n < 5; n++) {
    int col = (nb + n) * 16 + l16;
    float bv = b2[orig_ch(col)];
#pragma unroll
    for (int r = 0; r < 4; r++) {
      int tok = mf * 16 + quad * 4 + r;
      long a = (p0 + tok) * 160 + col;
      x3[a] = x3[a] + acc2[n][r] + bv;
    }
  }
}

// ---------------------------------------------------------------------------
// Kernel D: lin via bf16 MFMA -> plane-major yp [144][NPOS].
// ---------------------------------------------------------------------------
__global__ __launch_bounds__(256) void lin_mfma(const float* __restrict__ x3,
                                                const unsigned short* __restrict__ linf,
                                                const float* __restrict__ linb,
                                                float* __restrict__ yp) {
  __shared__ unsigned short xs[64 * 168];
  int tid = threadIdx.x;
  int p0 = blockIdx.x * 64;

  for (int idx = tid; idx < 5120; idx += 256) {
    int t = idx / 80, c2 = idx - t * 80;
    float2 v = *(const float2*)&x3[((long)(p0 + t)) * 160 + c2 * 2];
    *(ushort2*)&xs[t * 168 + c2 * 2] = make_ushort2(f2bf(v.x), f2bf(v.y));
  }
  __syncthreads();

  int w = tid >> 6, lane = tid & 63, quad = lane >> 4, l16 = lane & 15;
  floatx4 acc[9];
#pragma unroll
  for (int n = 0; n < 9; n++) acc[n] = (floatx4){0.f, 0.f, 0.f, 0.f};
  for (int ks = 0; ks < 5; ks++) {
    short8 a = *(const short8*)&xs[(w * 16 + l16) * 168 + ks * 32 + quad * 8];
    const short8* bp = (const short8*)linf + (ks * 9) * 64 + lane;
#pragma unroll
    for (int n = 0; n < 9; n++)
      acc[n] = __builtin_amdgcn_mfma_f32_16x16x32_bf16(a, bp[n * 64], acc[n], 0, 0, 0);
  }
#pragma unroll
  for (int n = 0; n < 9; n++) {
    int col = n * 16 + l16;
    float bv = linb[col];
    float4 o = make_float4(acc[n][0] + bv, acc[n][1] + bv, acc[n][2] + bv, acc[n][3] + bv);
    *(float4*)&yp[(long)col * NPOS + p0 + w * 16 + quad * 4] = o;
  }
}

// ---------------------------------------------------------------------------
// Kernel E: synthesis conv, sliding-window register blocking.
// ---------------------------------------------------------------------------
__global__ __launch_bounds__(256) void syn_kernel(const float* __restrict__ yp,
                                                  const float* __restrict__ fsyn,
                                                  float* __restrict__ yt) {
  __shared__ float tileS[24 * 120];
  __shared__ float fsl[729];
  int tid = threadIdx.x;
  int blk = blockIdx.x;
  int tile = blk % 7;
  int c = (blk / 7) % 16;
  int b = blk / 112;
  int ty0 = tile * 16;

  for (int i = tid; i < 729; i += 256) fsl[i] = fsyn[i];

  int ty = tid >> 4, txg = tid & 15;
  float acc[7];
#pragma unroll
  for (int w = 0; w < 7; w++) acc[w] = 0.f;

  for (int k = 0; k < 9; k++) {
    const float* plane = yp + (long)(k * 16 + c) * NPOS + (long)b * HH * WW;
    __syncthreads();
    for (int idx = tid; idx < 2880; idx += 256) {
      int ly = idx / 120, lx = idx - ly * 120;
      int gy = ty0 + ly - 4, gx = lx - 4;
      float v = 0.f;
      if (gy >= 0 && gy < HH && gx >= 0 && gx < WW) v = plane[gy * WW + gx];
      tileS[idx] = v;
    }
    __syncthreads();

#pragma unroll
    for (int ky = 0; ky < 9; ky++) {
      const float* row = &tileS[(ty + ky) * 120 + txg * 7];
      float rr[15];
#pragma unroll
      for (int i = 0; i < 15; i++) rr[i] = row[i];
      const float* fk = &fsl[k * 81 + ky * 9];
#pragma unroll
      for (int kx = 0; kx < 9; kx++) {
        float f = fk[kx];
#pragma unroll
        for (int w = 0; w < 7; w++) acc[w] += rr[kx + w] * f;
      }
    }
  }

  long obase = (long)c * NPOS + ((long)b * HH + (ty0 + ty)) * WW + txg * 7;
#pragma unroll
  for (int w = 0; w < 7; w++) yt[obase + w] = acc[w];
}

// ---------------------------------------------------------------------------
// Kernel F: final 1x1 conv from plane-major inputs -> out [B,16,H,W]
// ---------------------------------------------------------------------------
__global__ __launch_bounds__(256) void final_kernel(const float* __restrict__ yt,
                                                    const float* __restrict__ yp,
                                                    const float* __restrict__ convw,
                                                    const float* __restrict__ convb,
                                                    float* __restrict__ out) {
  long pos = (long)blockIdx.x * 256 + threadIdx.x;
  if (pos >= NPOS) return;
  int b = (int)(pos / (HH * WW));
  int hw = (int)(pos - (long)b * HH * WW);

  float acc[16];
#pragma unroll
  for (int co = 0; co < 16; co++) acc[co] = convb[co];
  for (int c = 0; c < 16; c++) {
    float v = yt[(long)c * NPOS + pos];
#pragma unroll
    for (int co = 0; co < 16; co++) acc[co] += v * convw[co * 160 + c];
  }
  for (int j = 0; j < 144; j++) {
    float v = yp[(long)j * NPOS + pos];
#pragma unroll
    for (int co = 0; co < 16; co++) acc[co] += v * convw[co * 160 + 16 + j];
  }
#pragma unroll
  for (int co = 0; co < 16; co++)
    out[(((long)b * 16 + co) * HH * WW) + hw] = acc[co];
}

// ---------------------------------------------------------------------------
extern "C" void kernel_launch(void* const* d_in, const int* in_sizes, int n_in,
                              void* d_out, int out_size, void* d_ws, size_t ws_size,
                              hipStream_t stream) {
  const float* x     = (const float*)d_in[0];
  const float* fana  = (const float*)d_in[1];
  const float* fsyn  = (const float*)d_in[2];
  const float* ln1g  = (const float*)d_in[3];
  const float* ln1b  = (const float*)d_in[4];
  const float* qkvw  = (const float*)d_in[5];
  const float* qkvb  = (const float*)d_in[6];
  const float* projw = (const float*)d_in[7];
  const float* projb = (const float*)d_in[8];
  const float* rpb   = (const float*)d_in[9];
  const float* ln2g  = (const float*)d_in[10];
  const float* ln2b  = (const float*)d_in[11];
  const float* w1    = (const float*)d_in[12];
  const float* b1    = (const float*)d_in[13];
  const float* w2    = (const float*)d_in[14];
  const float* b2    = (const float*)d_in[15];
  const float* linw  = (const float*)d_in[16];
  const float* linb  = (const float*)d_in[17];
  const float* convw = (const float*)d_in[18];
  const float* convb = (const float*)d_in[19];
  float* out = (float*)d_out;

  char* ws = (char*)d_ws;
  float* x3 = (float*)ws;                           // live whole run
  char* region2 = ws + 64225280;                    // time-shared:
  unsigned short* qkvbuf = (unsigned short*)region2;           // bf16 [NPOS x 480]
  unsigned short* packs  = (unsigned short*)(region2 + 96337920);
  unsigned short* qkvf = packs;
  unsigned short* projf = packs + 76800;
  unsigned short* w1f   = packs + 102400;
  unsigned short* w2f   = packs + 204800;
  unsigned short* linf  = packs + 307200;
  float* yp = (float*)region2;
  float* yt = (float*)ws;

  ana_kernel<<<BB * 49, 256, 0, stream>>>(x, fana, x3);
  pack1_kernel<<<90, 256, 0, stream>>>(linw, linf, 9, 144, 23040, 1, 0);
  for (int i = 0; i < 2; i++) {
    int shift = i ? (WIN / 2) : 0;
    pack4_kernel<<<1200, 256, 0, stream>>>(qkvw + i * 76800, projw + i * 25600,
                                           w1 + i * 102400, w2 + i * 102400,
                                           qkvf, projf, w1f, w2f);
    qkv_mfma<<<NPOS / 64, 256, 0, stream>>>(x3, ln1g + i * 160, ln1b + i * 160,
                                            qkvf, qkvb + i * 480, qkvbuf, shift);
    attn_core<<<BB * NWIN * HEADS, 128, 0, stream>>>(qkvbuf, rpb + i * 169 * 5, shift);
    proj_mfma<<<NPOS / 64, 256, 0, stream>>>(qkvbuf, projf, projb + i * 160, x3, shift);
    mlp_mfma<<<NPOS / 32, 256, 0, stream>>>(x3, ln2g + i * 160, ln2b + i * 160,
                                            w1f, b1 + i * 640, w2f, b2 + i * 160);
  }
  lin_mfma<<<NPOS / 64, 256, 0, stream>>>(x3, linf, linb, yp);
  syn_kernel<<<BB * 16 * 7, 256, 0, stream>>>(yp, fsyn, yt);
  final_kernel<<<(NPOS + 255) / 256, 256, 0, stream>>>(yt, yp, convw, convb, out);
}

// Round 16
// 1020.237 us; speedup vs baseline: 1.0737x; 1.0008x over previous
//
#include <hip/hip_runtime.h>
#include <hip/hip_bf16.h>
#include <math.h>

#define BB 8
#define CC 16
#define HH 112
#define WW 112
#define KK 9
#define FS 9
#define WIN 7
#define DIM 160
#define HEADS 5
#define HDIM 32
#define MLPD 640
#define NWIN 256          // (112/7)^2
#define NPOS (BB*HH*WW)   // 100352

typedef __attribute__((ext_vector_type(8))) short short8;
typedef __attribute__((ext_vector_type(4))) float floatx4;

__device__ __forceinline__ unsigned short f2bf(float f) {
  union { float f; unsigned u; } v; v.f = f;
  unsigned r = v.u + 0x7fffu + ((v.u >> 16) & 1u);
  return (unsigned short)(r >> 16);
}
__device__ __forceinline__ float bf2f(unsigned short u) {
  union { unsigned u; float f; } v; v.u = ((unsigned)u) << 16;
  return v.f;
}
// gelu tanh-approx, exp-based (same formula as jax.nn.gelu, no libm tanh)
__device__ __forceinline__ float gelu_f(float a) {
  float z = 0.7978845608028654f * (a + 0.044715f * a * a * a);
  return a * __builtin_amdgcn_rcpf(1.f + __expf(-2.f * z));
}
// x3 uses internal channel order ch' = c*10 + k (k=0..8 subbands, 9 = relu skip).
__device__ __forceinline__ int orig_ch(int ch) {
  int c = ch / 10, k = ch - c * 10;
  return (k < 9) ? k * 16 + c : 144 + c;
}

// ---------------------------------------------------------------------------
// Kernel A: relu + analysis filter bank -> x3 (permuted channels).
// R16: grid 784 = 392 tiles x 2 channel-halves. A thread owns one position's
// 8-channel half-row = 320 B = exactly 5 cache lines (line-aligned: 640B rows
// start line-aligned, 320 % 64 == 0), so no 64B line is shared between
// writers — the R8/R9 write-amp came from 160B (2.5-line) splits. 4-channel
// grouping retained: 13 LDS reads feed 36 FMAs.
// ---------------------------------------------------------------------------
__global__ __launch_bounds__(256) void ana_kernel(const float* __restrict__ x,
                                                  const float* __restrict__ fana,
                                                  float* __restrict__ x3) {
  __shared__ float tileS[8 * 576];   // 8 ch x 24x24
  __shared__ float fs[729];
  int tid = threadIdx.x;
  int blk = blockIdx.x;
  int b = blk / 98;
  int rem = blk - b * 98;
  int tile = rem >> 1;
  int half = rem & 1;                // channels half*8 .. half*8+7
  int y0 = (tile / 7) * 16, x0 = (tile % 7) * 16;
  int c0 = half * 8;

  for (int i = tid; i < 729; i += 256) fs[i] = fana[i];
  for (int idx = tid; idx < 4608; idx += 256) {
    int cl = idx / 576, r = idx - cl * 576;
    int ly = r / 24, lx = r - ly * 24;
    int gy = y0 + ly - 4, gx = x0 + lx - 4;
    float v = 0.f;
    if (gy >= 0 && gy < HH && gx >= 0 && gx < WW)
      v = fmaxf(x[(((long)b * CC + (c0 + cl)) * HH + gy) * WW + gx], 0.f);
    tileS[idx] = v;
  }
  __syncthreads();

  int ty = tid >> 4, tx = tid & 15;
  long obase = (((long)b * HH + (y0 + ty)) * WW + (x0 + tx)) * DIM;
  for (int cg = 0; cg < 2; cg++) {
    float acc[4][9];
#pragma unroll
    for (int cl = 0; cl < 4; cl++)
#pragma unroll
      for (int k = 0; k < 9; k++) acc[cl][k] = 0.f;
    const float* ts0 = &tileS[(cg * 4 + 0) * 576];
    const float* ts1 = &tileS[(cg * 4 + 1) * 576];
    const float* ts2 = &tileS[(cg * 4 + 2) * 576];
    const float* ts3 = &tileS[(cg * 4 + 3) * 576];
    for (int ky = 0; ky < 9; ky++) {
      for (int kx = 0; kx < 9; kx++) {
        int toff = (ty + ky) * 24 + (tx + kx);
        float f[9];
#pragma unroll
        for (int k = 0; k < 9; k++) f[k] = fs[k * 81 + ky * 9 + kx];
        float v0 = ts0[toff], v1 = ts1[toff], v2 = ts2[toff], v3 = ts3[toff];
#pragma unroll
        for (int k = 0; k < 9; k++) {
          acc[0][k] += v0 * f[k];
          acc[1][k] += v1 * f[k];
          acc[2][k] += v2 * f[k];
          acc[3][k] += v3 * f[k];
        }
      }
    }
    int center = (ty + 4) * 24 + (tx + 4);
    const float* tsp[4] = {ts0, ts1, ts2, ts3};
#pragma unroll
    for (int cl = 0; cl < 4; cl++) {
      int c = c0 + cg * 4 + cl;
      float skip = tsp[cl][center];
      float2* dst = (float2*)&x3[obase + c * 10];
      dst[0] = make_float2(acc[cl][0], acc[cl][1]);
      dst[1] = make_float2(acc[cl][2], acc[cl][3]);
      dst[2] = make_float2(acc[cl][4], acc[cl][5]);
      dst[3] = make_float2(acc[cl][6], acc[cl][7]);
      dst[4] = make_float2(acc[cl][8], skip);
    }
  }
}

// ---------------------------------------------------------------------------
// token_pos: window-ordered flat token p -> source position in [B,H,W]
// ---------------------------------------------------------------------------
__device__ __forceinline__ int token_pos(int p, int shift) {
  int w = p / 49;
  int t = p - w * 49;
  int b = w >> 8;
  int wid = w & 255;
  int wi = wid >> 4, wj = wid & 15;
  int iy = t / 7, ix = t - (t / 7) * 7;
  int hy = (wi * 7 + iy + shift) % HH;
  int wx = (wj * 7 + ix + shift) % WW;
  return (b * HH + hy) * WW + wx;
}

// ---------------------------------------------------------------------------
// Weight packing: fp32 [K x ncols] -> bf16 MFMA B-fragment-major layout.
// ---------------------------------------------------------------------------
__device__ __forceinline__ void pack_one(const float* __restrict__ src,
                                         unsigned short* __restrict__ dst,
                                         int nfcnt, int ncols, int nelems,
                                         int permK, int permN, int idx) {
  if (idx >= nelems) return;
  int j = idx & 7;
  int lane = (idx >> 3) & 63;
  int t = idx >> 9;
  int nf = t % nfcnt, ks = t / nfcnt;
  int k = ks * 32 + (lane >> 4) * 8 + j;
  int n = nf * 16 + (lane & 15);
  if (permK) k = orig_ch(k);
  if (permN) n = orig_ch(n);
  dst[idx] = f2bf(src[k * ncols + n]);
}

__global__ __launch_bounds__(256) void pack4_kernel(const float* __restrict__ qkvw,
                                                    const float* __restrict__ projw,
                                                    const float* __restrict__ w1,
                                                    const float* __restrict__ w2,
                                                    unsigned short* __restrict__ qkvf,
                                                    unsigned short* __restrict__ projf,
                                                    unsigned short* __restrict__ w1f,
                                                    unsigned short* __restrict__ w2f) {
  int blk = blockIdx.x, tid = threadIdx.x;
  if (blk < 300)      pack_one(qkvw,  qkvf,  30, 480, 76800,  1, 0, blk * 256 + tid);
  else if (blk < 400) pack_one(projw, projf, 10, 160, 25600,  0, 1, (blk - 300) * 256 + tid);
  else if (blk < 800) pack_one(w1,    w1f,   40, 640, 102400, 1, 0, (blk - 400) * 256 + tid);
  else                pack_one(w2,    w2f,   10, 160, 102400, 0, 1, (blk - 800) * 256 + tid);
}

__global__ __launch_bounds__(256) void pack1_kernel(const float* __restrict__ src,
                                                    unsigned short* __restrict__ dst,
                                                    int nfcnt, int ncols, int nelems,
                                                    int permK, int permN) {
  pack_one(src, dst, nfcnt, ncols, nelems, permK, permN, blockIdx.x * 256 + threadIdx.x);
}

// ---------------------------------------------------------------------------
// Kernel B1: LN1 + qkv GEMM via bf16 MFMA. 64 tokens/block (window-ordered).
// ---------------------------------------------------------------------------
__global__ __launch_bounds__(256) void qkv_mfma(const float* __restrict__ x3,
                                                const float* __restrict__ g,
                                                const float* __restrict__ bb,
                                                const unsigned short* __restrict__ qkvf,
                                                const float* __restrict__ qkvb,
                                                unsigned short* __restrict__ qkvbuf,
                                                int shift) {
  __shared__ unsigned short lnv[64 * 168];  // bf16, row stride 168

  int tid = threadIdx.x;
  int p0 = blockIdx.x * 64;

  {
    int t = tid >> 2, sub = tid & 3;
    int pos = token_pos(p0 + t, shift);
    const float* row = x3 + (long)pos * 160 + sub * 40;
    float xv[40];
    float s1 = 0.f, s2 = 0.f;
#pragma unroll
    for (int m = 0; m < 40; m++) { float v = row[m]; xv[m] = v; s1 += v; s2 += v * v; }
    s1 += __shfl_xor(s1, 1); s2 += __shfl_xor(s2, 1);
    s1 += __shfl_xor(s1, 2); s2 += __shfl_xor(s2, 2);
    float mu = s1 * (1.f / 160.f);
    float rs = rsqrtf(s2 * (1.f / 160.f) - mu * mu + 1e-5f);
#pragma unroll
    for (int m = 0; m < 40; m++) {
      int c = sub * 40 + m;
      int oc = orig_ch(c);
      lnv[t * 168 + c] = f2bf((xv[m] - mu) * rs * g[oc] + bb[oc]);
    }
  }
  __syncthreads();

  int w = tid >> 6, lane = tid & 63, quad = lane >> 4, l16 = lane & 15;

#pragma unroll
  for (int half = 0; half < 2; half++) {
    floatx4 acc[15];
#pragma unroll
    for (int n = 0; n < 15; n++) acc[n] = (floatx4){0.f, 0.f, 0.f, 0.f};
    for (int ks = 0; ks < 5; ks++) {
      short8 a = *(const short8*)&lnv[(w * 16 + l16) * 168 + ks * 32 + quad * 8];
      const short8* bp = (const short8*)qkvf + (ks * 30 + half * 15) * 64 + lane;
#pragma unroll
      for (int n = 0; n < 15; n++)
        acc[n] = __builtin_amdgcn_mfma_f32_16x16x32_bf16(a, bp[n * 64], acc[n], 0, 0, 0);
    }
#pragma unroll
    for (int n = 0; n < 15; n++) {
      int col = (half * 15 + n) * 16 + l16;
      float bv = qkvb[col];
#pragma unroll
      for (int r = 0; r < 4; r++) {
        int tok = p0 + w * 16 + quad * 4 + r;
        qkvbuf[(long)tok * 480 + col] = f2bf(acc[n][r] + bv);
      }
    }
  }
}

// ---------------------------------------------------------------------------
// Kernel B2: attention core via MFMA. One block per (window, head), 128 thr.
// ---------------------------------------------------------------------------
__global__ __launch_bounds__(128) void attn_core(unsigned short* __restrict__ qkvbuf,
                                                 const float* __restrict__ rpb,
                                                 int shift) {
  __shared__ unsigned short qs[64 * 40];   // bf16 [token][32], stride 40
  __shared__ unsigned short ks2[64 * 40];
  __shared__ unsigned short vT[32 * 68];   // bf16 [n][k], stride 68
  __shared__ float pb[64 * 68];            // scores / probs, stride 68
  __shared__ float bias_s[169];

  int tid = threadIdx.x;
  int bid = blockIdx.x;
  int w = bid / 5, h = bid - (bid / 5) * 5;
  int wid = w & 255;
  int wi = wid >> 4, wj = wid & 15;
  long base = (long)w * 49 * 480;

  for (int idx = tid; idx < 784; idx += 128) {
    int m = idx / 392;
    int r = idx - m * 392;
    int t = r >> 3, d4 = r & 7;
    ushort4 u = *(const ushort4*)&qkvbuf[base + (long)t * 480 + m * 160 + h * 32 + d4 * 4];
    unsigned short* dst = m ? ks2 : qs;
    *(ushort4*)&dst[t * 40 + d4 * 4] = u;
  }
  for (int idx = tid; idx < 392; idx += 128) {
    int t = idx >> 3, d4 = idx & 7;
    ushort4 u = *(const ushort4*)&qkvbuf[base + (long)t * 480 + 320 + h * 32 + d4 * 4];
    vT[(d4 * 4 + 0) * 68 + t] = u.x;
    vT[(d4 * 4 + 1) * 68 + t] = u.y;
    vT[(d4 * 4 + 2) * 68 + t] = u.z;
    vT[(d4 * 4 + 3) * 68 + t] = u.w;
  }
  for (int idx = tid; idx < 32 * 19; idx += 128) {
    int n = idx / 19, k2 = idx - n * 19;
    vT[n * 68 + 49 + k2] = 0;
  }
  for (int i = tid; i < 169; i += 128) bias_s[i] = rpb[i * 5 + h];
  __syncthreads();

  int wv = tid >> 6, lane = tid & 63, quad = lane >> 4, l16 = lane & 15;

  // ---- scores ----
#pragma unroll
  for (int mf2 = 0; mf2 < 2; mf2++) {
    int mf = wv * 2 + mf2;
    short8 a = *(const short8*)&qs[(mf * 16 + l16) * 40 + quad * 8];
    int iy[4], ix[4], ai[4], bi[4];
#pragma unroll
    for (int r = 0; r < 4; r++) {
      int i = mf * 16 + quad * 4 + r;
      iy[r] = i / 7; ix[r] = i - iy[r] * 7;
      if (shift) {
        int hri = wi * 7 + iy[r], wri = wj * 7 + ix[r];
        ai[r] = hri < 105 ? 0 : (hri < 109 ? 1 : 2);
        bi[r] = wri < 105 ? 0 : (wri < 109 ? 1 : 2);
      }
    }
#pragma unroll
    for (int nf = 0; nf < 4; nf++) {
      short8 b = *(const short8*)&ks2[(nf * 16 + l16) * 40 + quad * 8];
      floatx4 c = (floatx4){0.f, 0.f, 0.f, 0.f};
      c = __builtin_amdgcn_mfma_f32_16x16x32_bf16(a, b, c, 0, 0, 0);
      int jj = nf * 16 + l16;
      if (jj < 49) {
        int jy = jj / 7, jx = jj - jy * 7;
        int aj = 0, bj2 = 0;
        if (shift) {
          int hrj = wi * 7 + jy, wrj = wj * 7 + jx;
          aj = hrj < 105 ? 0 : (hrj < 109 ? 1 : 2);
          bj2 = wrj < 105 ? 0 : (wrj < 109 ? 1 : 2);
        }
#pragma unroll
        for (int r = 0; r < 4; r++) {
          int i = mf * 16 + quad * 4 + r;
          int rel = (iy[r] - jy + 6) * 13 + (ix[r] - jx + 6);
          rel = rel > 168 ? 168 : rel;
          float s = c[r] * 0.17677669529663687f + bias_s[rel];
          if (shift && (ai[r] != aj || bi[r] != bj2)) s -= 100.f;
          pb[i * 68 + jj] = s;
        }
      } else {
#pragma unroll
        for (int r = 0; r < 4; r++) {
          int i = mf * 16 + quad * 4 + r;
          pb[i * 68 + jj] = 0.f;
        }
      }
    }
  }
  __syncthreads();

  // ---- softmax rows 0..48 ----
  if (tid < 49) {
    float* row = &pb[tid * 68];
    float m = -1e30f;
    for (int j = 0; j < 49; j++) m = fmaxf(m, row[j]);
    float sum = 0.f;
    for (int j = 0; j < 49; j++) { float e = __expf(row[j] - m); row[j] = e; sum += e; }
    float inv = 1.f / sum;
    for (int j = 0; j < 49; j++) row[j] *= inv;
  }
  __syncthreads();

  // ---- PV ----
  short8 bv[2][2];
#pragma unroll
  for (int nf = 0; nf < 2; nf++)
#pragma unroll
    for (int ks = 0; ks < 2; ks++)
      bv[nf][ks] = *(const short8*)&vT[(nf * 16 + l16) * 68 + ks * 32 + quad * 8];

#pragma unroll
  for (int mf2 = 0; mf2 < 2; mf2++) {
    int mf = wv * 2 + mf2;
    short8 ap[2];
#pragma unroll
    for (int ks = 0; ks < 2; ks++) {
      const float* pr = &pb[(mf * 16 + l16) * 68 + ks * 32 + quad * 8];
      float4 plo = *(const float4*)pr;
      float4 phi = *(const float4*)(pr + 4);
      short8 av;
      av[0] = (short)f2bf(plo.x); av[1] = (short)f2bf(plo.y);
      av[2] = (short)f2bf(plo.z); av[3] = (short)f2bf(plo.w);
      av[4] = (short)f2bf(phi.x); av[5] = (short)f2bf(phi.y);
      av[6] = (short)f2bf(phi.z); av[7] = (short)f2bf(phi.w);
      ap[ks] = av;
    }
#pragma unroll
    for (int nf = 0; nf < 2; nf++) {
      floatx4 c = (floatx4){0.f, 0.f, 0.f, 0.f};
      c = __builtin_amdgcn_mfma_f32_16x16x32_bf16(ap[0], bv[nf][0], c, 0, 0, 0);
      c = __builtin_amdgcn_mfma_f32_16x16x32_bf16(ap[1], bv[nf][1], c, 0, 0, 0);
#pragma unroll
      for (int r = 0; r < 4; r++) {
        int row = mf * 16 + quad * 4 + r;
        if (row < 49)
          qkvbuf[base + (long)row * 480 + h * 32 + nf * 16 + l16] = f2bf(c[r]);
      }
    }
  }
}

// ---------------------------------------------------------------------------
// Kernel B3: proj via bf16 MFMA + residual scatter-add. 64 tokens/block.
// ---------------------------------------------------------------------------
__global__ __launch_bounds__(256) void proj_mfma(const unsigned short* __restrict__ qkvbuf,
                                                 const unsigned short* __restrict__ projf,
                                                 const float* __restrict__ projb,
                                                 float* __restrict__ x3,
                                                 int shift) {
  __shared__ unsigned short ao[64 * 168];
  __shared__ int spos[64];
  int tid = threadIdx.x;
  int p0 = blockIdx.x * 64;
  if (tid < 64) spos[tid] = token_pos(p0 + tid, shift);
  for (int idx = tid; idx < 10240; idx += 256) {
    int t = idx / 160, ch = idx - t * 160;
    ao[t * 168 + ch] = qkvbuf[(long)(p0 + t) * 480 + ch];
  }
  __syncthreads();

  int w = tid >> 6, lane = tid & 63, quad = lane >> 4, l16 = lane & 15;
  floatx4 acc[10];
#pragma unroll
  for (int n = 0; n < 10; n++) acc[n] = (floatx4){0.f, 0.f, 0.f, 0.f};
  for (int ks = 0; ks < 5; ks++) {
    short8 a = *(const short8*)&ao[(w * 16 + l16) * 168 + ks * 32 + quad * 8];
    const short8* bp = (const short8*)projf + (ks * 10) * 64 + lane;
#pragma unroll
    for (int n = 0; n < 10; n++)
      acc[n] = __builtin_amdgcn_mfma_f32_16x16x32_bf16(a, bp[n * 64], acc[n], 0, 0, 0);
  }
#pragma unroll
  for (int n = 0; n < 10; n++) {
    int col = n * 16 + l16;
    float bv = projb[orig_ch(col)];
#pragma unroll
    for (int r = 0; r < 4; r++) {
      int tl = w * 16 + quad * 4 + r;
      long a = (long)spos[tl] * DIM + col;
      x3[a] = x3[a] + acc[n][r] + bv;
    }
  }
}

// ---------------------------------------------------------------------------
// Kernel C: LN2 + MLP via bf16 MFMA. 32 tokens/block, 4 waves.
// ---------------------------------------------------------------------------
__global__ __launch_bounds__(256) void mlp_mfma(float* __restrict__ x3,
                                                const float* __restrict__ g,
                                                const float* __restrict__ bb,
                                                const unsigned short* __restrict__ w1f,
                                                const float* __restrict__ b1,
                                                const unsigned short* __restrict__ w2f,
                                                const float* __restrict__ b2) {
  __shared__ unsigned short lnv[32 * 168];
  __shared__ unsigned short h1s[32 * 648];

  int tid = threadIdx.x;
  long p0 = (long)blockIdx.x * 32;

  {
    int t = tid >> 3, sub = tid & 7;
    const float* row = x3 + (p0 + t) * 160 + sub * 20;
    float xv[20];
    float s1 = 0.f, s2 = 0.f;
#pragma unroll
    for (int m = 0; m < 20; m++) { float v = row[m]; xv[m] = v; s1 += v; s2 += v * v; }
#pragma unroll
    for (int m = 1; m < 8; m <<= 1) { s1 += __shfl_xor(s1, m); s2 += __shfl_xor(s2, m); }
    float mu = s1 * (1.f / 160.f);
    float rs = rsqrtf(s2 * (1.f / 160.f) - mu * mu + 1e-5f);
#pragma unroll
    for (int m = 0; m < 20; m++) {
      int c = sub * 20 + m;
      int oc = orig_ch(c);
      lnv[t * 168 + c] = f2bf((xv[m] - mu) * rs * g[oc] + bb[oc]);
    }
  }
  __syncthreads();

  int w = tid >> 6, lane = tid & 63, quad = lane >> 4, l16 = lane & 15;

  floatx4 acc[2][10];
#pragma unroll
  for (int mf = 0; mf < 2; mf++)
#pragma unroll
    for (int n = 0; n < 10; n++) acc[mf][n] = (floatx4){0.f, 0.f, 0.f, 0.f};

  for (int ks = 0; ks < 5; ks++) {
    short8 a0 = *(const short8*)&lnv[l16 * 168 + ks * 32 + quad * 8];
    short8 a1 = *(const short8*)&lnv[(16 + l16) * 168 + ks * 32 + quad * 8];
    const short8* bp = (const short8*)w1f + (ks * 40 + w * 10) * 64 + lane;
#pragma unroll
    for (int n = 0; n < 10; n++) {
      short8 bf = bp[n * 64];
      acc[0][n] = __builtin_amdgcn_mfma_f32_16x16x32_bf16(a0, bf, acc[0][n], 0, 0, 0);
      acc[1][n] = __builtin_amdgcn_mfma_f32_16x16x32_bf16(a1, bf, acc[1][n], 0, 0, 0);
    }
  }

#pragma unroll
  for (int mf = 0; mf < 2; mf++)
#pragma unroll
    for (int n = 0; n < 10; n++) {
      int col = w * 160 + n * 16 + l16;
      float bv = b1[col];
#pragma unroll
      for (int r = 0; r < 4; r++) {
        int tok = mf * 16 + quad * 4 + r;
        h1s[tok * 648 + col] = f2bf(gelu_f(acc[mf][n][r] + bv));
      }
    }
  __syncthreads();

  int mf = w & 1, nb = (w >> 1) * 5;
  floatx4 acc2[5];
#pragma unroll
  for (int n = 0; n < 5; n++) acc2[n] = (floatx4){0.f, 0.f, 0.f, 0.f};
  for (int ks = 0; ks < 20; ks++) {
    short8 a = *(const short8*)&h1s[(mf * 16 + l16) * 648 + ks * 32 + quad * 8];
    const short8* bp = (const short8*)w2f + (ks * 10 + nb) * 64 + lane;
#pragma unroll
    for (int n = 0; n < 5; n++)
      acc2[n] = __builtin_amdgcn_mfma_f32_16x16x32_bf16(a, bp[n * 64], acc2[n], 0, 0, 0);
  }

#pragma unroll
  for (int n = 0; n < 5; n++) {
    int col = (nb + n) * 16 + l16;
    float bv = b2[orig_ch(col)];
#pragma unroll
    for (int r = 0; r < 4; r++) {
      int tok = mf * 16 + quad * 4 + r;
      long a = (p0 + tok) * 160 + col;
      x3[a] = x3[a] + acc2[n][r] + bv;
    }
  }
}

// ---------------------------------------------------------------------------
// Kernel D: lin via bf16 MFMA -> plane-major yp [144][NPOS].
// ---------------------------------------------------------------------------
__global__ __launch_bounds__(256) void lin_mfma(const float* __restrict__ x3,
                                                const unsigned short* __restrict__ linf,
                                                const float* __restrict__ linb,
                                                float* __restrict__ yp) {
  __shared__ unsigned short xs[64 * 168];
  int tid = threadIdx.x;
  int p0 = blockIdx.x * 64;

  for (int idx = tid; idx < 5120; idx += 256) {
    int t = idx / 80, c2 = idx - t * 80;
    float2 v = *(const float2*)&x3[((long)(p0 + t)) * 160 + c2 * 2];
    *(ushort2*)&xs[t * 168 + c2 * 2] = make_ushort2(f2bf(v.x), f2bf(v.y));
  }
  __syncthreads();

  int w = tid >> 6, lane = tid & 63, quad = lane >> 4, l16 = lane & 15;
  floatx4 acc[9];
#pragma unroll
  for (int n = 0; n < 9; n++) acc[n] = (floatx4){0.f, 0.f, 0.f, 0.f};
  for (int ks = 0; ks < 5; ks++) {
    short8 a = *(const short8*)&xs[(w * 16 + l16) * 168 + ks * 32 + quad * 8];
    const short8* bp = (const short8*)linf + (ks * 9) * 64 + lane;
#pragma unroll
    for (int n = 0; n < 9; n++)
      acc[n] = __builtin_amdgcn_mfma_f32_16x16x32_bf16(a, bp[n * 64], acc[n], 0, 0, 0);
  }
#pragma unroll
  for (int n = 0; n < 9; n++) {
    int col = n * 16 + l16;
    float bv = linb[col];
    float4 o = make_float4(acc[n][0] + bv, acc[n][1] + bv, acc[n][2] + bv, acc[n][3] + bv);
    *(float4*)&yp[(long)col * NPOS + p0 + w * 16 + quad * 4] = o;
  }
}

// ---------------------------------------------------------------------------
// Kernel E: synthesis conv, sliding-window register blocking.
// ---------------------------------------------------------------------------
__global__ __launch_bounds__(256) void syn_kernel(const float* __restrict__ yp,
                                                  const float* __restrict__ fsyn,
                                                  float* __restrict__ yt) {
  __shared__ float tileS[24 * 120];
  __shared__ float fsl[729];
  int tid = threadIdx.x;
  int blk = blockIdx.x;
  int tile = blk % 7;
  int c = (blk / 7) % 16;
  int b = blk / 112;
  int ty0 = tile * 16;

  for (int i = tid; i < 729; i += 256) fsl[i] = fsyn[i];

  int ty = tid >> 4, txg = tid & 15;
  float acc[7];
#pragma unroll
  for (int w = 0; w < 7; w++) acc[w] = 0.f;

  for (int k = 0; k < 9; k++) {
    const float* plane = yp + (long)(k * 16 + c) * NPOS + (long)b * HH * WW;
    __syncthreads();
    for (int idx = tid; idx < 2880; idx += 256) {
      int ly = idx / 120, lx = idx - ly * 120;
      int gy = ty0 + ly - 4, gx = lx - 4;
      float v = 0.f;
      if (gy >= 0 && gy < HH && gx >= 0 && gx < WW) v = plane[gy * WW + gx];
      tileS[idx] = v;
    }
    __syncthreads();

#pragma unroll
    for (int ky = 0; ky < 9; ky++) {
      const float* row = &tileS[(ty + ky) * 120 + txg * 7];
      float rr[15];
#pragma unroll
      for (int i = 0; i < 15; i++) rr[i] = row[i];
      const float* fk = &fsl[k * 81 + ky * 9];
#pragma unroll
      for (int kx = 0; kx < 9; kx++) {
        float f = fk[kx];
#pragma unroll
        for (int w = 0; w < 7; w++) acc[w] += rr[kx + w] * f;
      }
    }
  }

  long obase = (long)c * NPOS + ((long)b * HH + (ty0 + ty)) * WW + txg * 7;
#pragma unroll
  for (int w = 0; w < 7; w++) yt[obase + w] = acc[w];
}

// ---------------------------------------------------------------------------
// Kernel F: final 1x1 conv from plane-major inputs -> out [B,16,H,W]
// ---------------------------------------------------------------------------
__global__ __launch_bounds__(256) void final_kernel(const float* __restrict__ yt,
                                                    const float* __restrict__ yp,
                                                    const float* __restrict__ convw,
                                                    const float* __restrict__ convb,
                                                    float* __restrict__ out) {
  long pos = (long)blockIdx.x * 256 + threadIdx.x;
  if (pos >= NPOS) return;
  int b = (int)(pos / (HH * WW));
  int hw = (int)(pos - (long)b * HH * WW);

  float acc[16];
#pragma unroll
  for (int co = 0; co < 16; co++) acc[co] = convb[co];
  for (int c = 0; c < 16; c++) {
    float v = yt[(long)c * NPOS + pos];
#pragma unroll
    for (int co = 0; co < 16; co++) acc[co] += v * convw[co * 160 + c];
  }
  for (int j = 0; j < 144; j++) {
    float v = yp[(long)j * NPOS + pos];
#pragma unroll
    for (int co = 0; co < 16; co++) acc[co] += v * convw[co * 160 + 16 + j];
  }
#pragma unroll
  for (int co = 0; co < 16; co++)
    out[(((long)b * 16 + co) * HH * WW) + hw] = acc[co];
}

// ---------------------------------------------------------------------------
extern "C" void kernel_launch(void* const* d_in, const int* in_sizes, int n_in,
                              void* d_out, int out_size, void* d_ws, size_t ws_size,
                              hipStream_t stream) {
  const float* x     = (const float*)d_in[0];
  const float* fana  = (const float*)d_in[1];
  const float* fsyn  = (const float*)d_in[2];
  const float* ln1g  = (const float*)d_in[3];
  const float* ln1b  = (const float*)d_in[4];
  const float* qkvw  = (const float*)d_in[5];
  const float* qkvb  = (const float*)d_in[6];
  const float* projw = (const float*)d_in[7];
  const float* projb = (const float*)d_in[8];
  const float* rpb   = (const float*)d_in[9];
  const float* ln2g  = (const float*)d_in[10];
  const float* ln2b  = (const float*)d_in[11];
  const float* w1    = (const float*)d_in[12];
  const float* b1    = (const float*)d_in[13];
  const float* w2    = (const float*)d_in[14];
  const float* b2    = (const float*)d_in[15];
  const float* linw  = (const float*)d_in[16];
  const float* linb  = (const float*)d_in[17];
  const float* convw = (const float*)d_in[18];
  const float* convb = (const float*)d_in[19];
  float* out = (float*)d_out;

  char* ws = (char*)d_ws;
  float* x3 = (float*)ws;                           // live whole run
  char* region2 = ws + 64225280;                    // time-shared:
  unsigned short* qkvbuf = (unsigned short*)region2;           // bf16 [NPOS x 480]
  unsigned short* packs  = (unsigned short*)(region2 + 96337920);
  unsigned short* qkvf = packs;
  unsigned short* projf = packs + 76800;
  unsigned short* w1f   = packs + 102400;
  unsigned short* w2f   = packs + 204800;
  unsigned short* linf  = packs + 307200;
  float* yp = (float*)region2;
  float* yt = (float*)ws;

  ana_kernel<<<BB * 98, 256, 0, stream>>>(x, fana, x3);
  pack1_kernel<<<90, 256, 0, stream>>>(linw, linf, 9, 144, 23040, 1, 0);
  for (int i = 0; i < 2; i++) {
    int shift = i ? (WIN / 2) : 0;
    pack4_kernel<<<1200, 256, 0, stream>>>(qkvw + i * 76800, projw + i * 25600,
                                           w1 + i * 102400, w2 + i * 102400,
                                           qkvf, projf, w1f, w2f);
    qkv_mfma<<<NPOS / 64, 256, 0, stream>>>(x3, ln1g + i * 160, ln1b + i * 160,
                                            qkvf, qkvb + i * 480, qkvbuf, shift);
    attn_core<<<BB * NWIN * HEADS, 128, 0, stream>>>(qkvbuf, rpb + i * 169 * 5, shift);
    proj_mfma<<<NPOS / 64, 256, 0, stream>>>(qkvbuf, projf, projb + i * 160, x3, shift);
    mlp_mfma<<<NPOS / 32, 256, 0, stream>>>(x3, ln2g + i * 160, ln2b + i * 160,
                                            w1f, b1 + i * 640, w2f, b2 + i * 160);
  }
  lin_mfma<<<NPOS / 64, 256, 0, stream>>>(x3, linf, linb, yp);
  syn_kernel<<<BB * 16 * 7, 256, 0, stream>>>(yp, fsyn, yt);
  final_kernel<<<(NPOS + 255) / 256, 256, 0, stream>>>(yt, yp, convw, convb, out);
}

// Round 17
// 1011.801 us; speedup vs baseline: 1.0827x; 1.0083x over previous
//
#include <hip/hip_runtime.h>
#include <hip/hip_bf16.h>
#include <math.h>

#define BB 8
#define CC 16
#define HH 112
#define WW 112
#define KK 9
#define FS 9
#define WIN 7
#define DIM 160
#define HEADS 5
#define HDIM 32
#define MLPD 640
#define NWIN 256          // (112/7)^2
#define NPOS (BB*HH*WW)   // 100352

typedef __attribute__((ext_vector_type(8))) short short8;
typedef __attribute__((ext_vector_type(4))) float floatx4;

__device__ __forceinline__ unsigned short f2bf(float f) {
  union { float f; unsigned u; } v; v.f = f;
  unsigned r = v.u + 0x7fffu + ((v.u >> 16) & 1u);
  return (unsigned short)(r >> 16);
}
__device__ __forceinline__ float bf2f(unsigned short u) {
  union { unsigned u; float f; } v; v.u = ((unsigned)u) << 16;
  return v.f;
}
// gelu tanh-approx, exp-based (same formula as jax.nn.gelu, no libm tanh)
__device__ __forceinline__ float gelu_f(float a) {
  float z = 0.7978845608028654f * (a + 0.044715f * a * a * a);
  return a * __builtin_amdgcn_rcpf(1.f + __expf(-2.f * z));
}
// x3 uses internal channel order ch' = c*10 + k (k=0..8 subbands, 9 = relu skip).
__device__ __forceinline__ int orig_ch(int ch) {
  int c = ch / 10, k = ch - c * 10;
  return (k < 9) ? k * 16 + c : 144 + c;
}

// ---------------------------------------------------------------------------
// Kernel A: relu + analysis filter bank -> x3 (permuted channels).
// grid 784 = 392 tiles x 2 channel-halves; a thread owns one position's
// 8-channel half-row = 320 B = 5 whole cache lines (no line shared between
// writers; 160B splits caused ~12x RMW). 4-channel grouping: 13 LDS reads
// feed 36 FMAs.
// ---------------------------------------------------------------------------
__global__ __launch_bounds__(256) void ana_kernel(const float* __restrict__ x,
                                                  const float* __restrict__ fana,
                                                  float* __restrict__ x3) {
  __shared__ float tileS[8 * 576];   // 8 ch x 24x24
  __shared__ float fs[729];
  int tid = threadIdx.x;
  int blk = blockIdx.x;
  int b = blk / 98;
  int rem = blk - b * 98;
  int tile = rem >> 1;
  int half = rem & 1;                // channels half*8 .. half*8+7
  int y0 = (tile / 7) * 16, x0 = (tile % 7) * 16;
  int c0 = half * 8;

  for (int i = tid; i < 729; i += 256) fs[i] = fana[i];
  for (int idx = tid; idx < 4608; idx += 256) {
    int cl = idx / 576, r = idx - cl * 576;
    int ly = r / 24, lx = r - ly * 24;
    int gy = y0 + ly - 4, gx = x0 + lx - 4;
    float v = 0.f;
    if (gy >= 0 && gy < HH && gx >= 0 && gx < WW)
      v = fmaxf(x[(((long)b * CC + (c0 + cl)) * HH + gy) * WW + gx], 0.f);
    tileS[idx] = v;
  }
  __syncthreads();

  int ty = tid >> 4, tx = tid & 15;
  long obase = (((long)b * HH + (y0 + ty)) * WW + (x0 + tx)) * DIM;
  for (int cg = 0; cg < 2; cg++) {
    float acc[4][9];
#pragma unroll
    for (int cl = 0; cl < 4; cl++)
#pragma unroll
      for (int k = 0; k < 9; k++) acc[cl][k] = 0.f;
    const float* ts0 = &tileS[(cg * 4 + 0) * 576];
    const float* ts1 = &tileS[(cg * 4 + 1) * 576];
    const float* ts2 = &tileS[(cg * 4 + 2) * 576];
    const float* ts3 = &tileS[(cg * 4 + 3) * 576];
    for (int ky = 0; ky < 9; ky++) {
      for (int kx = 0; kx < 9; kx++) {
        int toff = (ty + ky) * 24 + (tx + kx);
        float f[9];
#pragma unroll
        for (int k = 0; k < 9; k++) f[k] = fs[k * 81 + ky * 9 + kx];
        float v0 = ts0[toff], v1 = ts1[toff], v2 = ts2[toff], v3 = ts3[toff];
#pragma unroll
        for (int k = 0; k < 9; k++) {
          acc[0][k] += v0 * f[k];
          acc[1][k] += v1 * f[k];
          acc[2][k] += v2 * f[k];
          acc[3][k] += v3 * f[k];
        }
      }
    }
    int center = (ty + 4) * 24 + (tx + 4);
    const float* tsp[4] = {ts0, ts1, ts2, ts3};
#pragma unroll
    for (int cl = 0; cl < 4; cl++) {
      int c = c0 + cg * 4 + cl;
      float skip = tsp[cl][center];
      float2* dst = (float2*)&x3[obase + c * 10];
      dst[0] = make_float2(acc[cl][0], acc[cl][1]);
      dst[1] = make_float2(acc[cl][2], acc[cl][3]);
      dst[2] = make_float2(acc[cl][4], acc[cl][5]);
      dst[3] = make_float2(acc[cl][6], acc[cl][7]);
      dst[4] = make_float2(acc[cl][8], skip);
    }
  }
}

// ---------------------------------------------------------------------------
// token_pos: window-ordered flat token p -> source position in [B,H,W]
// ---------------------------------------------------------------------------
__device__ __forceinline__ int token_pos(int p, int shift) {
  int w = p / 49;
  int t = p - w * 49;
  int b = w >> 8;
  int wid = w & 255;
  int wi = wid >> 4, wj = wid & 15;
  int iy = t / 7, ix = t - (t / 7) * 7;
  int hy = (wi * 7 + iy + shift) % HH;
  int wx = (wj * 7 + ix + shift) % WW;
  return (b * HH + hy) * WW + wx;
}

// ---------------------------------------------------------------------------
// Weight packing: fp32 [K x ncols] -> bf16 MFMA B-fragment-major layout.
// ---------------------------------------------------------------------------
__device__ __forceinline__ void pack_one(const float* __restrict__ src,
                                         unsigned short* __restrict__ dst,
                                         int nfcnt, int ncols, int nelems,
                                         int permK, int permN, int idx) {
  if (idx >= nelems) return;
  int j = idx & 7;
  int lane = (idx >> 3) & 63;
  int t = idx >> 9;
  int nf = t % nfcnt, ks = t / nfcnt;
  int k = ks * 32 + (lane >> 4) * 8 + j;
  int n = nf * 16 + (lane & 15);
  if (permK) k = orig_ch(k);
  if (permN) n = orig_ch(n);
  dst[idx] = f2bf(src[k * ncols + n]);
}

__global__ __launch_bounds__(256) void pack4_kernel(const float* __restrict__ qkvw,
                                                    const float* __restrict__ projw,
                                                    const float* __restrict__ w1,
                                                    const float* __restrict__ w2,
                                                    unsigned short* __restrict__ qkvf,
                                                    unsigned short* __restrict__ projf,
                                                    unsigned short* __restrict__ w1f,
                                                    unsigned short* __restrict__ w2f) {
  int blk = blockIdx.x, tid = threadIdx.x;
  if (blk < 300)      pack_one(qkvw,  qkvf,  30, 480, 76800,  1, 0, blk * 256 + tid);
  else if (blk < 400) pack_one(projw, projf, 10, 160, 25600,  0, 1, (blk - 300) * 256 + tid);
  else if (blk < 800) pack_one(w1,    w1f,   40, 640, 102400, 1, 0, (blk - 400) * 256 + tid);
  else                pack_one(w2,    w2f,   10, 160, 102400, 0, 1, (blk - 800) * 256 + tid);
}

__global__ __launch_bounds__(256) void pack1_kernel(const float* __restrict__ src,
                                                    unsigned short* __restrict__ dst,
                                                    int nfcnt, int ncols, int nelems,
                                                    int permK, int permN) {
  pack_one(src, dst, nfcnt, ncols, nelems, permK, permN, blockIdx.x * 256 + threadIdx.x);
}

// ---------------------------------------------------------------------------
// Kernel B1: LN1 + qkv GEMM via bf16 MFMA. 64 tokens/block (window-ordered).
// ---------------------------------------------------------------------------
__global__ __launch_bounds__(256) void qkv_mfma(const float* __restrict__ x3,
                                                const float* __restrict__ g,
                                                const float* __restrict__ bb,
                                                const unsigned short* __restrict__ qkvf,
                                                const float* __restrict__ qkvb,
                                                unsigned short* __restrict__ qkvbuf,
                                                int shift) {
  __shared__ unsigned short lnv[64 * 168];  // bf16, row stride 168

  int tid = threadIdx.x;
  int p0 = blockIdx.x * 64;

  {
    int t = tid >> 2, sub = tid & 3;
    int pos = token_pos(p0 + t, shift);
    const float* row = x3 + (long)pos * 160 + sub * 40;
    float xv[40];
    float s1 = 0.f, s2 = 0.f;
#pragma unroll
    for (int m = 0; m < 40; m++) { float v = row[m]; xv[m] = v; s1 += v; s2 += v * v; }
    s1 += __shfl_xor(s1, 1); s2 += __shfl_xor(s2, 1);
    s1 += __shfl_xor(s1, 2); s2 += __shfl_xor(s2, 2);
    float mu = s1 * (1.f / 160.f);
    float rs = rsqrtf(s2 * (1.f / 160.f) - mu * mu + 1e-5f);
#pragma unroll
    for (int m = 0; m < 40; m++) {
      int c = sub * 40 + m;
      int oc = orig_ch(c);
      lnv[t * 168 + c] = f2bf((xv[m] - mu) * rs * g[oc] + bb[oc]);
    }
  }
  __syncthreads();

  int w = tid >> 6, lane = tid & 63, quad = lane >> 4, l16 = lane & 15;

#pragma unroll
  for (int half = 0; half < 2; half++) {
    floatx4 acc[15];
#pragma unroll
    for (int n = 0; n < 15; n++) acc[n] = (floatx4){0.f, 0.f, 0.f, 0.f};
    for (int ks = 0; ks < 5; ks++) {
      short8 a = *(const short8*)&lnv[(w * 16 + l16) * 168 + ks * 32 + quad * 8];
      const short8* bp = (const short8*)qkvf + (ks * 30 + half * 15) * 64 + lane;
#pragma unroll
      for (int n = 0; n < 15; n++)
        acc[n] = __builtin_amdgcn_mfma_f32_16x16x32_bf16(a, bp[n * 64], acc[n], 0, 0, 0);
    }
#pragma unroll
    for (int n = 0; n < 15; n++) {
      int col = (half * 15 + n) * 16 + l16;
      float bv = qkvb[col];
#pragma unroll
      for (int r = 0; r < 4; r++) {
        int tok = p0 + w * 16 + quad * 4 + r;
        qkvbuf[(long)tok * 480 + col] = f2bf(acc[n][r] + bv);
      }
    }
  }
}

// ---------------------------------------------------------------------------
// Kernel B2: attention core via MFMA. One block per (window, head), 128 thr.
// ---------------------------------------------------------------------------
__global__ __launch_bounds__(128) void attn_core(unsigned short* __restrict__ qkvbuf,
                                                 const float* __restrict__ rpb,
                                                 int shift) {
  __shared__ unsigned short qs[64 * 40];   // bf16 [token][32], stride 40
  __shared__ unsigned short ks2[64 * 40];
  __shared__ unsigned short vT[32 * 68];   // bf16 [n][k], stride 68
  __shared__ float pb[64 * 68];            // scores / probs, stride 68
  __shared__ float bias_s[169];

  int tid = threadIdx.x;
  int bid = blockIdx.x;
  int w = bid / 5, h = bid - (bid / 5) * 5;
  int wid = w & 255;
  int wi = wid >> 4, wj = wid & 15;
  long base = (long)w * 49 * 480;

  for (int idx = tid; idx < 784; idx += 128) {
    int m = idx / 392;
    int r = idx - m * 392;
    int t = r >> 3, d4 = r & 7;
    ushort4 u = *(const ushort4*)&qkvbuf[base + (long)t * 480 + m * 160 + h * 32 + d4 * 4];
    unsigned short* dst = m ? ks2 : qs;
    *(ushort4*)&dst[t * 40 + d4 * 4] = u;
  }
  for (int idx = tid; idx < 392; idx += 128) {
    int t = idx >> 3, d4 = idx & 7;
    ushort4 u = *(const ushort4*)&qkvbuf[base + (long)t * 480 + 320 + h * 32 + d4 * 4];
    vT[(d4 * 4 + 0) * 68 + t] = u.x;
    vT[(d4 * 4 + 1) * 68 + t] = u.y;
    vT[(d4 * 4 + 2) * 68 + t] = u.z;
    vT[(d4 * 4 + 3) * 68 + t] = u.w;
  }
  for (int idx = tid; idx < 32 * 19; idx += 128) {
    int n = idx / 19, k2 = idx - n * 19;
    vT[n * 68 + 49 + k2] = 0;
  }
  for (int i = tid; i < 169; i += 128) bias_s[i] = rpb[i * 5 + h];
  __syncthreads();

  int wv = tid >> 6, lane = tid & 63, quad = lane >> 4, l16 = lane & 15;

  // ---- scores ----
#pragma unroll
  for (int mf2 = 0; mf2 < 2; mf2++) {
    int mf = wv * 2 + mf2;
    short8 a = *(const short8*)&qs[(mf * 16 + l16) * 40 + quad * 8];
    int iy[4], ix[4], ai[4], bi[4];
#pragma unroll
    for (int r = 0; r < 4; r++) {
      int i = mf * 16 + quad * 4 + r;
      iy[r] = i / 7; ix[r] = i - iy[r] * 7;
      if (shift) {
        int hri = wi * 7 + iy[r], wri = wj * 7 + ix[r];
        ai[r] = hri < 105 ? 0 : (hri < 109 ? 1 : 2);
        bi[r] = wri < 105 ? 0 : (wri < 109 ? 1 : 2);
      }
    }
#pragma unroll
    for (int nf = 0; nf < 4; nf++) {
      short8 b = *(const short8*)&ks2[(nf * 16 + l16) * 40 + quad * 8];
      floatx4 c = (floatx4){0.f, 0.f, 0.f, 0.f};
      c = __builtin_amdgcn_mfma_f32_16x16x32_bf16(a, b, c, 0, 0, 0);
      int jj = nf * 16 + l16;
      if (jj < 49) {
        int jy = jj / 7, jx = jj - jy * 7;
        int aj = 0, bj2 = 0;
        if (shift) {
          int hrj = wi * 7 + jy, wrj = wj * 7 + jx;
          aj = hrj < 105 ? 0 : (hrj < 109 ? 1 : 2);
          bj2 = wrj < 105 ? 0 : (wrj < 109 ? 1 : 2);
        }
#pragma unroll
        for (int r = 0; r < 4; r++) {
          int i = mf * 16 + quad * 4 + r;
          int rel = (iy[r] - jy + 6) * 13 + (ix[r] - jx + 6);
          rel = rel > 168 ? 168 : rel;
          float s = c[r] * 0.17677669529663687f + bias_s[rel];
          if (shift && (ai[r] != aj || bi[r] != bj2)) s -= 100.f;
          pb[i * 68 + jj] = s;
        }
      } else {
#pragma unroll
        for (int r = 0; r < 4; r++) {
          int i = mf * 16 + quad * 4 + r;
          pb[i * 68 + jj] = 0.f;
        }
      }
    }
  }
  __syncthreads();

  // ---- softmax rows 0..48 ----
  if (tid < 49) {
    float* row = &pb[tid * 68];
    float m = -1e30f;
    for (int j = 0; j < 49; j++) m = fmaxf(m, row[j]);
    float sum = 0.f;
    for (int j = 0; j < 49; j++) { float e = __expf(row[j] - m); row[j] = e; sum += e; }
    float inv = 1.f / sum;
    for (int j = 0; j < 49; j++) row[j] *= inv;
  }
  __syncthreads();

  // ---- PV ----
  short8 bv[2][2];
#pragma unroll
  for (int nf = 0; nf < 2; nf++)
#pragma unroll
    for (int ks = 0; ks < 2; ks++)
      bv[nf][ks] = *(const short8*)&vT[(nf * 16 + l16) * 68 + ks * 32 + quad * 8];

#pragma unroll
  for (int mf2 = 0; mf2 < 2; mf2++) {
    int mf = wv * 2 + mf2;
    short8 ap[2];
#pragma unroll
    for (int ks = 0; ks < 2; ks++) {
      const float* pr = &pb[(mf * 16 + l16) * 68 + ks * 32 + quad * 8];
      float4 plo = *(const float4*)pr;
      float4 phi = *(const float4*)(pr + 4);
      short8 av;
      av[0] = (short)f2bf(plo.x); av[1] = (short)f2bf(plo.y);
      av[2] = (short)f2bf(plo.z); av[3] = (short)f2bf(plo.w);
      av[4] = (short)f2bf(phi.x); av[5] = (short)f2bf(phi.y);
      av[6] = (short)f2bf(phi.z); av[7] = (short)f2bf(phi.w);
      ap[ks] = av;
    }
#pragma unroll
    for (int nf = 0; nf < 2; nf++) {
      floatx4 c = (floatx4){0.f, 0.f, 0.f, 0.f};
      c = __builtin_amdgcn_mfma_f32_16x16x32_bf16(ap[0], bv[nf][0], c, 0, 0, 0);
      c = __builtin_amdgcn_mfma_f32_16x16x32_bf16(ap[1], bv[nf][1], c, 0, 0, 0);
#pragma unroll
      for (int r = 0; r < 4; r++) {
        int row = mf * 16 + quad * 4 + r;
        if (row < 49)
          qkvbuf[base + (long)row * 480 + h * 32 + nf * 16 + l16] = f2bf(c[r]);
      }
    }
  }
}

// ---------------------------------------------------------------------------
// Kernel B3+C fused: proj + residual + LN2 + MLP, 32 tokens/block, 4 waves.
// xnew = x3 + proj(attn_out) stays in LDS between proj and MLP (saves proj's
// x3 write + mlp's two x3 reads, ~190 MB/layer). Wave w: m-frag mf=w&1,
// N-half nh=w>>1 for proj & fc2; fc1 splits N per wave (R11 scheme).
// u16 buffer is ao (attn-out bf16) then lnv (barrier-separated).
// ---------------------------------------------------------------------------
__global__ __launch_bounds__(256) void projmlp_mfma(const unsigned short* __restrict__ qkvbuf,
                                                    const unsigned short* __restrict__ projf,
                                                    const float* __restrict__ projb,
                                                    float* __restrict__ x3,
                                                    const float* __restrict__ g,
                                                    const float* __restrict__ bb,
                                                    const unsigned short* __restrict__ w1f,
                                                    const float* __restrict__ b1,
                                                    const unsigned short* __restrict__ w2f,
                                                    const float* __restrict__ b2,
                                                    int shift) {
  __shared__ float xs[32 * 168];           // fp32 xnew, stride 168
  __shared__ unsigned short u16[32 * 168]; // ao, then lnv
  __shared__ unsigned short h1s[32 * 648];
  __shared__ int spos[32];

  int tid = threadIdx.x;
  int p0 = blockIdx.x * 32;
  if (tid < 32) spos[tid] = token_pos(p0 + tid, shift);
  for (int idx = tid; idx < 5120; idx += 256) {
    int t = idx / 160, ch = idx - t * 160;
    u16[t * 168 + ch] = qkvbuf[(long)(p0 + t) * 480 + ch];
  }
  __syncthreads();

  int w = tid >> 6, lane = tid & 63, quad = lane >> 4, l16 = lane & 15;
  int mf = w & 1, nb = (w >> 1) * 5;   // m-frag / N-half used by proj and fc2

  // ---- proj: 5 N-frags per wave, K=160 ----
  floatx4 pacc[5];
#pragma unroll
  for (int n = 0; n < 5; n++) pacc[n] = (floatx4){0.f, 0.f, 0.f, 0.f};
  for (int ks = 0; ks < 5; ks++) {
    short8 a = *(const short8*)&u16[(mf * 16 + l16) * 168 + ks * 32 + quad * 8];
    const short8* bp = (const short8*)projf + (ks * 10 + nb) * 64 + lane;
#pragma unroll
    for (int n = 0; n < 5; n++)
      pacc[n] = __builtin_amdgcn_mfma_f32_16x16x32_bf16(a, bp[n * 64], pacc[n], 0, 0, 0);
  }
  __syncthreads();  // all ao reads done before lnv reuses u16

  // ---- residual: xnew = x3 + proj + bias -> xs (LDS) ----
#pragma unroll
  for (int n = 0; n < 5; n++) {
    int col = (nb + n) * 16 + l16;
    float bv = projb[orig_ch(col)];
#pragma unroll
    for (int r = 0; r < 4; r++) {
      int tok = mf * 16 + quad * 4 + r;
      float xv = x3[(long)spos[tok] * 160 + col] + pacc[n][r] + bv;
      xs[tok * 168 + col] = xv;
    }
  }
  __syncthreads();

  // ---- LN2 from xs -> lnv (u16), scalar reads (vec-LN is banned) ----
  {
    int t = tid >> 3, sub = tid & 7;
    const float* row = &xs[t * 168 + sub * 20];
    float xv[20];
    float s1 = 0.f, s2 = 0.f;
#pragma unroll
    for (int m = 0; m < 20; m++) { float v = row[m]; xv[m] = v; s1 += v; s2 += v * v; }
#pragma unroll
    for (int m = 1; m < 8; m <<= 1) { s1 += __shfl_xor(s1, m); s2 += __shfl_xor(s2, m); }
    float mu = s1 * (1.f / 160.f);
    float rs = rsqrtf(s2 * (1.f / 160.f) - mu * mu + 1e-5f);
#pragma unroll
    for (int m = 0; m < 20; m++) {
      int c = sub * 20 + m;
      int oc = orig_ch(c);
      u16[t * 168 + c] = f2bf((xv[m] - mu) * rs * g[oc] + bb[oc]);
    }
  }
  __syncthreads();

  // ---- fc1: wave w -> cols [w*160, w*160+160) (R11 scheme) ----
  floatx4 acc[2][10];
#pragma unroll
  for (int m2 = 0; m2 < 2; m2++)
#pragma unroll
    for (int n = 0; n < 10; n++) acc[m2][n] = (floatx4){0.f, 0.f, 0.f, 0.f};

  for (int ks = 0; ks < 5; ks++) {
    short8 a0 = *(const short8*)&u16[l16 * 168 + ks * 32 + quad * 8];
    short8 a1 = *(const short8*)&u16[(16 + l16) * 168 + ks * 32 + quad * 8];
    const short8* bp = (const short8*)w1f + (ks * 40 + w * 10) * 64 + lane;
#pragma unroll
    for (int n = 0; n < 10; n++) {
      short8 bf = bp[n * 64];
      acc[0][n] = __builtin_amdgcn_mfma_f32_16x16x32_bf16(a0, bf, acc[0][n], 0, 0, 0);
      acc[1][n] = __builtin_amdgcn_mfma_f32_16x16x32_bf16(a1, bf, acc[1][n], 0, 0, 0);
    }
  }

#pragma unroll
  for (int m2 = 0; m2 < 2; m2++)
#pragma unroll
    for (int n = 0; n < 10; n++) {
      int col = w * 160 + n * 16 + l16;
      float bv = b1[col];
#pragma unroll
      for (int r = 0; r < 4; r++) {
        int tok = m2 * 16 + quad * 4 + r;
        h1s[tok * 648 + col] = f2bf(gelu_f(acc[m2][n][r] + bv));
      }
    }
  __syncthreads();

  // ---- fc2: m-frag mf, N-frags nb..nb+4, full K=640 ----
  floatx4 acc2[5];
#pragma unroll
  for (int n = 0; n < 5; n++) acc2[n] = (floatx4){0.f, 0.f, 0.f, 0.f};
  for (int ks = 0; ks < 20; ks++) {
    short8 a = *(const short8*)&h1s[(mf * 16 + l16) * 648 + ks * 32 + quad * 8];
    const short8* bp = (const short8*)w2f + (ks * 10 + nb) * 64 + lane;
#pragma unroll
    for (int n = 0; n < 5; n++)
      acc2[n] = __builtin_amdgcn_mfma_f32_16x16x32_bf16(a, bp[n * 64], acc2[n], 0, 0, 0);
  }

  // ---- writeout: x3 = xnew + fc2 + bias (scattered rows, block-exclusive) ----
#pragma unroll
  for (int n = 0; n < 5; n++) {
    int col = (nb + n) * 16 + l16;
    float bv = b2[orig_ch(col)];
#pragma unroll
    for (int r = 0; r < 4; r++) {
      int tok = mf * 16 + quad * 4 + r;
      x3[(long)spos[tok] * 160 + col] = xs[tok * 168 + col] + acc2[n][r] + bv;
    }
  }
}

// ---------------------------------------------------------------------------
// Kernel D: lin via bf16 MFMA -> plane-major yp [144][NPOS].
// ---------------------------------------------------------------------------
__global__ __launch_bounds__(256) void lin_mfma(const float* __restrict__ x3,
                                                const unsigned short* __restrict__ linf,
                                                const float* __restrict__ linb,
                                                float* __restrict__ yp) {
  __shared__ unsigned short xs[64 * 168];
  int tid = threadIdx.x;
  int p0 = blockIdx.x * 64;

  for (int idx = tid; idx < 5120; idx += 256) {
    int t = idx / 80, c2 = idx - t * 80;
    float2 v = *(const float2*)&x3[((long)(p0 + t)) * 160 + c2 * 2];
    *(ushort2*)&xs[t * 168 + c2 * 2] = make_ushort2(f2bf(v.x), f2bf(v.y));
  }
  __syncthreads();

  int w = tid >> 6, lane = tid & 63, quad = lane >> 4, l16 = lane & 15;
  floatx4 acc[9];
#pragma unroll
  for (int n = 0; n < 9; n++) acc[n] = (floatx4){0.f, 0.f, 0.f, 0.f};
  for (int ks = 0; ks < 5; ks++) {
    short8 a = *(const short8*)&xs[(w * 16 + l16) * 168 + ks * 32 + quad * 8];
    const short8* bp = (const short8*)linf + (ks * 9) * 64 + lane;
#pragma unroll
    for (int n = 0; n < 9; n++)
      acc[n] = __builtin_amdgcn_mfma_f32_16x16x32_bf16(a, bp[n * 64], acc[n], 0, 0, 0);
  }
#pragma unroll
  for (int n = 0; n < 9; n++) {
    int col = n * 16 + l16;
    float bv = linb[col];
    float4 o = make_float4(acc[n][0] + bv, acc[n][1] + bv, acc[n][2] + bv, acc[n][3] + bv);
    *(float4*)&yp[(long)col * NPOS + p0 + w * 16 + quad * 4] = o;
  }
}

// ---------------------------------------------------------------------------
// Kernel E: synthesis conv, sliding-window register blocking.
// ---------------------------------------------------------------------------
__global__ __launch_bounds__(256) void syn_kernel(const float* __restrict__ yp,
                                                  const float* __restrict__ fsyn,
                                                  float* __restrict__ yt) {
  __shared__ float tileS[24 * 120];
  __shared__ float fsl[729];
  int tid = threadIdx.x;
  int blk = blockIdx.x;
  int tile = blk % 7;
  int c = (blk / 7) % 16;
  int b = blk / 112;
  int ty0 = tile * 16;

  for (int i = tid; i < 729; i += 256) fsl[i] = fsyn[i];

  int ty = tid >> 4, txg = tid & 15;
  float acc[7];
#pragma unroll
  for (int w = 0; w < 7; w++) acc[w] = 0.f;

  for (int k = 0; k < 9; k++) {
    const float* plane = yp + (long)(k * 16 + c) * NPOS + (long)b * HH * WW;
    __syncthreads();
    for (int idx = tid; idx < 2880; idx += 256) {
      int ly = idx / 120, lx = idx - ly * 120;
      int gy = ty0 + ly - 4, gx = lx - 4;
      float v = 0.f;
      if (gy >= 0 && gy < HH && gx >= 0 && gx < WW) v = plane[gy * WW + gx];
      tileS[idx] = v;
    }
    __syncthreads();

#pragma unroll
    for (int ky = 0; ky < 9; ky++) {
      const float* row = &tileS[(ty + ky) * 120 + txg * 7];
      float rr[15];
#pragma unroll
      for (int i = 0; i < 15; i++) rr[i] = row[i];
      const float* fk = &fsl[k * 81 + ky * 9];
#pragma unroll
      for (int kx = 0; kx < 9; kx++) {
        float f = fk[kx];
#pragma unroll
        for (int w = 0; w < 7; w++) acc[w] += rr[kx + w] * f;
      }
    }
  }

  long obase = (long)c * NPOS + ((long)b * HH + (ty0 + ty)) * WW + txg * 7;
#pragma unroll
  for (int w = 0; w < 7; w++) yt[obase + w] = acc[w];
}

// ---------------------------------------------------------------------------
// Kernel F: final 1x1 conv from plane-major inputs -> out [B,16,H,W]
// ---------------------------------------------------------------------------
__global__ __launch_bounds__(256) void final_kernel(const float* __restrict__ yt,
                                                    const float* __restrict__ yp,
                                                    const float* __restrict__ convw,
                                                    const float* __restrict__ convb,
                                                    float* __restrict__ out) {
  long pos = (long)blockIdx.x * 256 + threadIdx.x;
  if (pos >= NPOS) return;
  int b = (int)(pos / (HH * WW));
  int hw = (int)(pos - (long)b * HH * WW);

  float acc[16];
#pragma unroll
  for (int co = 0; co < 16; co++) acc[co] = convb[co];
  for (int c = 0; c < 16; c++) {
    float v = yt[(long)c * NPOS + pos];
#pragma unroll
    for (int co = 0; co < 16; co++) acc[co] += v * convw[co * 160 + c];
  }
  for (int j = 0; j < 144; j++) {
    float v = yp[(long)j * NPOS + pos];
#pragma unroll
    for (int co = 0; co < 16; co++) acc[co] += v * convw[co * 160 + 16 + j];
  }
#pragma unroll
  for (int co = 0; co < 16; co++)
    out[(((long)b * 16 + co) * HH * WW) + hw] = acc[co];
}

// ---------------------------------------------------------------------------
extern "C" void kernel_launch(void* const* d_in, const int* in_sizes, int n_in,
                              void* d_out, int out_size, void* d_ws, size_t ws_size,
                              hipStream_t stream) {
  const float* x     = (const float*)d_in[0];
  const float* fana  = (const float*)d_in[1];
  const float* fsyn  = (const float*)d_in[2];
  const float* ln1g  = (const float*)d_in[3];
  const float* ln1b  = (const float*)d_in[4];
  const float* qkvw  = (const float*)d_in[5];
  const float* qkvb  = (const float*)d_in[6];
  const float* projw = (const float*)d_in[7];
  const float* projb = (const float*)d_in[8];
  const float* rpb   = (const float*)d_in[9];
  const float* ln2g  = (const float*)d_in[10];
  const float* ln2b  = (const float*)d_in[11];
  const float* w1    = (const float*)d_in[12];
  const float* b1    = (const float*)d_in[13];
  const float* w2    = (const float*)d_in[14];
  const float* b2    = (const float*)d_in[15];
  const float* linw  = (const float*)d_in[16];
  const float* linb  = (const float*)d_in[17];
  const float* convw = (const float*)d_in[18];
  const float* convb = (const float*)d_in[19];
  float* out = (float*)d_out;

  char* ws = (char*)d_ws;
  float* x3 = (float*)ws;                           // live whole run
  char* region2 = ws + 64225280;                    // time-shared:
  unsigned short* qkvbuf = (unsigned short*)region2;           // bf16 [NPOS x 480]
  unsigned short* packs  = (unsigned short*)(region2 + 96337920);
  unsigned short* qkvf = packs;
  unsigned short* projf = packs + 76800;
  unsigned short* w1f   = packs + 102400;
  unsigned short* w2f   = packs + 204800;
  unsigned short* linf  = packs + 307200;
  float* yp = (float*)region2;
  float* yt = (float*)ws;

  ana_kernel<<<BB * 98, 256, 0, stream>>>(x, fana, x3);
  pack1_kernel<<<90, 256, 0, stream>>>(linw, linf, 9, 144, 23040, 1, 0);
  for (int i = 0; i < 2; i++) {
    int shift = i ? (WIN / 2) : 0;
    pack4_kernel<<<1200, 256, 0, stream>>>(qkvw + i * 76800, projw + i * 25600,
                                           w1 + i * 102400, w2 + i * 102400,
                                           qkvf, projf, w1f, w2f);
    qkv_mfma<<<NPOS / 64, 256, 0, stream>>>(x3, ln1g + i * 160, ln1b + i * 160,
                                            qkvf, qkvb + i * 480, qkvbuf, shift);
    attn_core<<<BB * NWIN * HEADS, 128, 0, stream>>>(qkvbuf, rpb + i * 169 * 5, shift);
    projmlp_mfma<<<NPOS / 32, 256, 0, stream>>>(qkvbuf, projf, projb + i * 160, x3,
                                                ln2g + i * 160, ln2b + i * 160,
                                                w1f, b1 + i * 640, w2f, b2 + i * 160,
                                                shift);
  }
  lin_mfma<<<NPOS / 64, 256, 0, stream>>>(x3, linf, linb, yp);
  syn_kernel<<<BB * 16 * 7, 256, 0, stream>>>(yp, fsyn, yt);
  final_kernel<<<(NPOS + 255) / 256, 256, 0, stream>>>(yt, yp, convw, convb, out);
}